// Round 4
// baseline (1182.223 us; speedup 1.0000x reference)
//
#include <hip/hip_runtime.h>
#include <math.h>

// ---------------------------------------------------------------------------
// Round 4: 2 waves/SIMD. Weights+params in LDS (120.8 KB) + per-wave TH
// scratch only (4.3 KB x 8 waves). Persistent activations (z, y, x_proj) live
// as B-fragment registers, built from C-layout regs via a 4-lane quad shuffle
// (c2b). 512-thread blocks -> 8 waves/CU = 2/SIMD. k/v layers fused to read
// each A-frag once for both y- and z-token inputs (layerB2).
// ---------------------------------------------------------------------------

constexpr int STEPS = 16;
constexpr int INDIM = 200;

typedef __attribute__((ext_vector_type(8))) short bfrag8;   // 8 bf16 = 4 VGPR
typedef __attribute__((ext_vector_type(4))) float f32x4;
typedef __attribute__((ext_vector_type(4))) short s16x4;

// ---- global workspace frag indices (prepack output; 1 frag = 512 shorts) ----
constexpr int FB_WIN  = 0;    // W_in: mt(4) x kt(7)
constexpr int NFRAG   = 140;
constexpr int NPARAM  = 1544;

// ---- LDS-resident steady frag indices (= global index - 28) ----
constexpr int LB_ZQ   = 0;
constexpr int LB_ZK   = 8;
constexpr int LB_ZV   = 16;
constexpr int LB_ZOUT = 24;
constexpr int LB_ZF1  = 32;
constexpr int LB_ZF2  = 48;
constexpr int LB_YV   = 64;
constexpr int LB_YOUT = 72;
constexpr int LB_YF1  = 80;
constexpr int LB_YF2  = 96;
constexpr int NSTEADY = 112;

// ---- packed param float offsets ----
constexpr int PB_BIN   = 0;
constexpr int PB_GIN   = 64;
constexpr int PB_BEIN  = 128;
constexpr int PB_ZINB  = 192;
constexpr int PB_ZOUTB = 384;
constexpr int PB_ZF1B  = 448;
constexpr int PB_ZF2B  = 576;
constexpr int PB_ZN1G  = 640;
constexpr int PB_ZN1B  = 704;
constexpr int PB_ZN2G  = 768;
constexpr int PB_ZN2B  = 832;
constexpr int PB_YVB   = 896;
constexpr int PB_YOUTB = 960;
constexpr int PB_YF1B  = 1024;
constexpr int PB_YF2B  = 1152;
constexpr int PB_YN1G  = 1216;
constexpr int PB_YN1B  = 1280;
constexpr int PB_YN2G  = 1344;
constexpr int PB_YN2B  = 1408;
constexpr int PB_WOUT  = 1472;
constexpr int PB_BOUT  = 1536;

// ---- LDS arena layout (shorts) ----
constexpr int S64      = 72;
constexpr int S128     = 136;
constexpr int L_W      = 0;                       // 112 frags = 57,344 shorts
constexpr int L_P      = 57344;                   // 3,088 shorts
constexpr int L_ACT    = 60432;                   // 8 waves x TH
constexpr int WAVE_SH  = 2176;                    // TH only: max(16*72, 16*136)
constexpr int NWAVE    = 8;
constexpr int ARENA_SH = L_ACT + NWAVE * WAVE_SH; // 77,840 shorts = 155,680 B

struct Params {
  const float *x, *W_in, *b_in, *g_in, *be_in;
  const float *z_in_w, *z_in_b, *z_out_w, *z_out_b;
  const float *z_ffn_w1, *z_ffn_b1, *z_ffn_w2, *z_ffn_b2;
  const float *zn1_g, *zn1_b, *zn2_g, *zn2_b;
  const float *y_in_w, *y_in_b, *y_out_w, *y_out_b;
  const float *y_ffn_w1, *y_ffn_b1, *y_ffn_w2, *y_ffn_b2;
  const float *yn1_g, *yn1_b, *yn2_g, *yn2_b;
  const float *W_out, *b_out;
  float *out;
  int nrows;
};

__device__ __forceinline__ ushort f2bf(float f) {
  uint u = __float_as_uint(f);
  u += 0x7FFFu + ((u >> 16) & 1u);
  return (ushort)(u >> 16);
}
__device__ __forceinline__ float dot4(f32x4 a, f32x4 b) {
  return a.x * b.x + a.y * b.y + a.z * b.z + a.w * b.w;
}
__device__ __forceinline__ void stc(short* buf, int stride, int mt, int q,
                                    int s, f32x4 c) {
  s16x4 v;
  v.x = (short)f2bf(c.x); v.y = (short)f2bf(c.y);
  v.z = (short)f2bf(c.z); v.w = (short)f2bf(c.w);
  *(s16x4*)(buf + s * stride + mt * 16 + q * 4) = v;
}

// ---- C-layout regs (4 x f32x4, 64 feats of sample s spread over q-lanes)
// ---- -> 2 MFMA B-frags (bf16), pure register/cross-lane transform.
// Verified mapping: b[kt] lane(q,s) holds feats kt*32+q*8+j; source quad for
// j-half comes from lane qc=2*(q&1)(+1), register mt=2*kt+(q>>1).
__device__ __forceinline__ void c2b(const f32x4 c[4], bfrag8& b0, bfrag8& b1,
                                    int lane) {
  uint p[8];
#pragma unroll
  for (int mt = 0; mt < 4; ++mt) {
    p[2 * mt]     = (uint)f2bf(c[mt].x) | ((uint)f2bf(c[mt].y) << 16);
    p[2 * mt + 1] = (uint)f2bf(c[mt].z) | ((uint)f2bf(c[mt].w) << 16);
  }
  const int srcA = (lane & 15) | ((lane & 16) << 1);  // s + 32*(q&1)
  const int srcB = srcA + 16;
  const bool odd = (lane & 32) != 0;                  // q>=2 wants mt 1,3
  uint ev0 = p[0], ev1 = p[1], ev2 = p[4], ev3 = p[5];
  uint od0 = p[2], od1 = p[3], od2 = p[6], od3 = p[7];
  uint rA0, rA1, rA2, rA3, rB0, rB1, rB2, rB3;
  {
    uint e, o;
    e = (uint)__shfl((int)ev0, srcA); o = (uint)__shfl((int)od0, srcA); rA0 = odd ? o : e;
    e = (uint)__shfl((int)ev1, srcA); o = (uint)__shfl((int)od1, srcA); rA1 = odd ? o : e;
    e = (uint)__shfl((int)ev2, srcA); o = (uint)__shfl((int)od2, srcA); rA2 = odd ? o : e;
    e = (uint)__shfl((int)ev3, srcA); o = (uint)__shfl((int)od3, srcA); rA3 = odd ? o : e;
    e = (uint)__shfl((int)ev0, srcB); o = (uint)__shfl((int)od0, srcB); rB0 = odd ? o : e;
    e = (uint)__shfl((int)ev1, srcB); o = (uint)__shfl((int)od1, srcB); rB1 = odd ? o : e;
    e = (uint)__shfl((int)ev2, srcB); o = (uint)__shfl((int)od2, srcB); rB2 = odd ? o : e;
    e = (uint)__shfl((int)ev3, srcB); o = (uint)__shfl((int)od3, srcB); rB3 = odd ? o : e;
  }
  union U { uint u[4]; bfrag8 b; };
  U u0, u1;
  u0.u[0] = rA0; u0.u[1] = rA1; u0.u[2] = rB0; u0.u[3] = rB1;
  u1.u[0] = rA2; u1.u[1] = rA3; u1.u[2] = rB2; u1.u[3] = rB3;
  b0 = u0.b; b1 = u1.b;
}

// c[mt] = W * X^T + bias; B from LDS (TH scratch).
template <int MT, int KT>
__device__ __forceinline__ void layerN(const short* in, int stride,
                                       const short* lw, int fbase,
                                       const float* bias, f32x4* c,
                                       int lane, int q, int s) {
  bfrag8 bf[KT];
#pragma unroll
  for (int kt = 0; kt < KT; ++kt)
    bf[kt] = *(const bfrag8*)(in + s * stride + kt * 32 + q * 8);
#pragma unroll
  for (int mt = 0; mt < MT; ++mt)
    c[mt] = *(const f32x4*)(bias + mt * 16 + q * 4);
#pragma unroll
  for (int mt = 0; mt < MT; ++mt) {
#pragma unroll
    for (int kt = 0; kt < KT; ++kt) {
      bfrag8 af = *(const bfrag8*)(lw + (fbase + mt * KT + kt) * 512 + lane * 8);
      c[mt] = __builtin_amdgcn_mfma_f32_16x16x32_bf16(af, bf[kt], c[mt], 0, 0, 0);
    }
  }
}

// B from registers.
template <int MT>
__device__ __forceinline__ void layerB(const bfrag8* bf, const short* lw,
                                       int fbase, const float* bias, f32x4* c,
                                       int lane, int q) {
#pragma unroll
  for (int mt = 0; mt < MT; ++mt)
    c[mt] = *(const f32x4*)(bias + mt * 16 + q * 4);
#pragma unroll
  for (int mt = 0; mt < MT; ++mt) {
#pragma unroll
    for (int kt = 0; kt < 2; ++kt) {
      bfrag8 af = *(const bfrag8*)(lw + (fbase + mt * 2 + kt) * 512 + lane * 8);
      c[mt] = __builtin_amdgcn_mfma_f32_16x16x32_bf16(af, bf[kt], c[mt], 0, 0, 0);
    }
  }
}

// Two B inputs through the same weights: A-frag read once, 2 indep MFMA chains.
template <int MT>
__device__ __forceinline__ void layerB2(const bfrag8* bfA, const bfrag8* bfB,
                                        const short* lw, int fbase,
                                        const float* bias, f32x4* cA, f32x4* cB,
                                        int lane, int q) {
#pragma unroll
  for (int mt = 0; mt < MT; ++mt) {
    f32x4 b4 = *(const f32x4*)(bias + mt * 16 + q * 4);
    cA[mt] = b4; cB[mt] = b4;
  }
#pragma unroll
  for (int mt = 0; mt < MT; ++mt) {
#pragma unroll
    for (int kt = 0; kt < 2; ++kt) {
      bfrag8 af = *(const bfrag8*)(lw + (fbase + mt * 2 + kt) * 512 + lane * 8);
      cA[mt] = __builtin_amdgcn_mfma_f32_16x16x32_bf16(af, bfA[kt], cA[mt], 0, 0, 0);
      cB[mt] = __builtin_amdgcn_mfma_f32_16x16x32_bf16(af, bfB[kt], cB[mt], 0, 0, 0);
    }
  }
}

__device__ __forceinline__ void lnorm_c(f32x4 c[4], const float* g,
                                        const float* b, int q) {
  float sm = 0.f;
#pragma unroll
  for (int mt = 0; mt < 4; ++mt) sm += c[mt].x + c[mt].y + c[mt].z + c[mt].w;
  sm += __shfl_xor(sm, 16); sm += __shfl_xor(sm, 32);
  float mean = sm * (1.f / 64.f);
  float vs = 0.f;
#pragma unroll
  for (int mt = 0; mt < 4; ++mt) {
    f32x4 d = c[mt];
    d.x -= mean; d.y -= mean; d.z -= mean; d.w -= mean;
    c[mt] = d;
    vs += d.x * d.x + d.y * d.y + d.z * d.z + d.w * d.w;
  }
  vs += __shfl_xor(vs, 16); vs += __shfl_xor(vs, 32);
  float rs = rsqrtf(vs * (1.f / 64.f) + 1e-5f);
#pragma unroll
  for (int mt = 0; mt < 4; ++mt) {
    f32x4 g4 = *(const f32x4*)(g + mt * 16 + q * 4);
    f32x4 b4 = *(const f32x4*)(b + mt * 16 + q * 4);
    f32x4 v = c[mt];
    v.x = v.x * rs * g4.x + b4.x; v.y = v.y * rs * g4.y + b4.y;
    v.z = v.z * rs * g4.z + b4.z; v.w = v.w * rs * g4.w + b4.w;
    c[mt] = v;
  }
}

__device__ __forceinline__ float gelu1(float x) {
  float ax = fabsf(x) * 0.70710678118654752f;
  float t = __builtin_amdgcn_rcpf(1.0f + 0.3275911f * ax);
  float poly =
      ((((1.061405429f * t - 1.453152027f) * t + 1.421413741f) * t -
        0.284496736f) * t + 0.254829592f) * t;
  float e = __expf(-ax * ax);
  float erfv = copysignf(1.0f - poly * e, x);
  return 0.5f * x * (1.0f + erfv);
}

// ---------------------------------------------------------------------------
// prepack: weights -> A-frag bf16 order; params -> packed fp32 array
// ---------------------------------------------------------------------------
__global__ void prepack_kernel(Params p, ushort* wf) {
  int f = blockIdx.x;
  int lane = threadIdx.x;

  if (f == NFRAG) {
    float* pw = (float*)(wf + (size_t)NFRAG * 512);
    for (int t = lane; t < NPARAM; t += 64) {
      float v = 0.f;
      if      (t < 64)   v = p.b_in[t];
      else if (t < 128)  v = p.g_in[t - 64];
      else if (t < 192)  v = p.be_in[t - 128];
      else if (t < 384)  v = p.z_in_b[t - 192];
      else if (t < 448)  v = p.z_out_b[t - 384];
      else if (t < 576)  v = p.z_ffn_b1[t - 448];
      else if (t < 640)  v = p.z_ffn_b2[t - 576];
      else if (t < 704)  v = p.zn1_g[t - 640];
      else if (t < 768)  v = p.zn1_b[t - 704];
      else if (t < 832)  v = p.zn2_g[t - 768];
      else if (t < 896)  v = p.zn2_b[t - 832];
      else if (t < 960)  v = p.y_in_b[128 + t - 896];
      else if (t < 1024) v = p.y_out_b[t - 960];
      else if (t < 1152) v = p.y_ffn_b1[t - 1024];
      else if (t < 1216) v = p.y_ffn_b2[t - 1152];
      else if (t < 1280) v = p.yn1_g[t - 1216];
      else if (t < 1344) v = p.yn1_b[t - 1280];
      else if (t < 1408) v = p.yn2_g[t - 1344];
      else if (t < 1472) v = p.yn2_b[t - 1408];
      else if (t < 1536) v = p.W_out[t - 1472];
      else if (t == 1536) v = p.b_out[0];
      pw[t] = v;
    }
    return;
  }

  int q = lane >> 4, r = lane & 15;
  const float* src; int K, mt, kt, l;
  if (f < 28)        { src = p.W_in;                K = 200; mt = f / 7;  kt = f % 7; }
  else if (f < 36)   { l = f - 28;  src = p.z_in_w;            K = 64;  mt = l / 2; kt = l % 2; }
  else if (f < 44)   { l = f - 36;  src = p.z_in_w + 64 * 64;  K = 64;  mt = l / 2; kt = l % 2; }
  else if (f < 52)   { l = f - 44;  src = p.z_in_w + 128 * 64; K = 64;  mt = l / 2; kt = l % 2; }
  else if (f < 60)   { l = f - 52;  src = p.z_out_w;           K = 64;  mt = l / 2; kt = l % 2; }
  else if (f < 76)   { l = f - 60;  src = p.z_ffn_w1;          K = 64;  mt = l / 2; kt = l % 2; }
  else if (f < 92)   { l = f - 76;  src = p.z_ffn_w2;          K = 128; mt = l / 4; kt = l % 4; }
  else if (f < 100)  { l = f - 92;  src = p.y_in_w + 128 * 64; K = 64;  mt = l / 2; kt = l % 2; }
  else if (f < 108)  { l = f - 100; src = p.y_out_w;           K = 64;  mt = l / 2; kt = l % 2; }
  else if (f < 124)  { l = f - 108; src = p.y_ffn_w1;          K = 64;  mt = l / 2; kt = l % 2; }
  else               { l = f - 124; src = p.y_ffn_w2;          K = 128; mt = l / 4; kt = l % 4; }

  int row = mt * 16 + r;
  int col = kt * 32 + q * 8;
  bfrag8 o;
#pragma unroll
  for (int j = 0; j < 8; ++j) {
    int cc = col + j;
    float v = (cc < K) ? src[(size_t)row * K + cc] : 0.0f;
    o[j] = (short)f2bf(v);
  }
  *(bfrag8*)(wf + (size_t)f * 512 + lane * 8) = o;
}

// ---------------------------------------------------------------------------
// main kernel: 512 thr (8 waves) x 256 blocks, weights in LDS, acts in regs
// ---------------------------------------------------------------------------
__global__ __launch_bounds__(512, 2) void trm_mfma_kernel(Params p,
                                                          const ushort* wf) {
  __shared__ __align__(16) short arena[ARENA_SH];
  const int tid = threadIdx.x;
  const int wave = tid >> 6, lane = tid & 63;
  const int q = lane >> 4, s = lane & 15;

  // ---- stage steady weights + params into LDS (once per block) ----
  {
    const uint4* srcw = (const uint4*)(wf + (size_t)28 * 512);
    uint4* dstw = (uint4*)(arena + L_W);
    for (int i = tid; i < NSTEADY * 64; i += 512) dstw[i] = srcw[i];
    const uint4* srcp = (const uint4*)(wf + (size_t)NFRAG * 512);
    uint4* dstp = (uint4*)(arena + L_P);
    for (int i = tid; i < NPARAM / 4; i += 512) dstp[i] = srcp[i];
  }
  __syncthreads();  // the only barrier

  const short* LW = arena + L_W;
  const float* P  = (const float*)(arena + L_P);
  short* TH = arena + L_ACT + wave * WAVE_SH;

  const int chunks = (p.nrows + 127) / 128;
  for (int ic = blockIdx.x; ic < chunks; ic += gridDim.x) {
    const int row0 = ic * 128 + wave * 16;
    int row = row0 + s;
    if (row >= p.nrows) row = p.nrows - 1;

    // ---- x_proj = gelu(ln(x @ W_in^T + b_in)); stays in registers ----
    bfrag8 xpB[2];
    {
      const float* xr = p.x + (size_t)row * INDIM;
      bfrag8 xb[7];
#pragma unroll
      for (int kt = 0; kt < 7; ++kt) {
        int k0i = kt * 32 + q * 8;
        bfrag8 t;
        if (kt < 6 || q == 0) {
          f32x4 lo = *(const f32x4*)(xr + k0i);
          f32x4 hi = *(const f32x4*)(xr + k0i + 4);
          t[0] = (short)f2bf(lo.x); t[1] = (short)f2bf(lo.y);
          t[2] = (short)f2bf(lo.z); t[3] = (short)f2bf(lo.w);
          t[4] = (short)f2bf(hi.x); t[5] = (short)f2bf(hi.y);
          t[6] = (short)f2bf(hi.z); t[7] = (short)f2bf(hi.w);
        } else {
#pragma unroll
          for (int j = 0; j < 8; ++j) t[j] = 0;
        }
        xb[kt] = t;
      }
      f32x4 c[4];
#pragma unroll
      for (int mt = 0; mt < 4; ++mt)
        c[mt] = *(const f32x4*)(P + PB_BIN + mt * 16 + q * 4);
#pragma unroll
      for (int mt = 0; mt < 4; ++mt)
#pragma unroll
        for (int kt = 0; kt < 7; ++kt) {
          bfrag8 af =
              *(const bfrag8*)(wf + (size_t)(FB_WIN + mt * 7 + kt) * 512 + lane * 8);
          c[mt] = __builtin_amdgcn_mfma_f32_16x16x32_bf16(af, xb[kt], c[mt], 0, 0, 0);
        }
      lnorm_c(c, P + PB_GIN, P + PB_BEIN, q);
#pragma unroll
      for (int mt = 0; mt < 4; ++mt) {
        c[mt].x = gelu1(c[mt].x); c[mt].y = gelu1(c[mt].y);
        c[mt].z = gelu1(c[mt].z); c[mt].w = gelu1(c[mt].w);
      }
      c2b(c, xpB[0], xpB[1], lane);
    }

    // ---- k0/v0 in registers; zero state ----
    f32x4 k0r[4], v0r[4], zC[4], yC[4];
    bfrag8 zB[2], yB[2];
    layerB<4>(xpB, LW, LB_ZK, P + PB_ZINB + 64, k0r, lane, q);
    layerB<4>(xpB, LW, LB_ZV, P + PB_ZINB + 128, v0r, lane, q);
    {
      f32x4 zf; zf.x = 0.f; zf.y = 0.f; zf.z = 0.f; zf.w = 0.f;
#pragma unroll
      for (int mt = 0; mt < 4; ++mt) { zC[mt] = zf; yC[mt] = zf; }
#pragma unroll
      for (int kt = 0; kt < 2; ++kt) {
        bfrag8 t;
#pragma unroll
        for (int j = 0; j < 8; ++j) t[j] = 0;
        zB[kt] = t; yB[kt] = t;
      }
    }

    // ---- 16 recursive steps (LDS weights + register acts) ----
    for (int st = 0; st < STEPS; ++st) {
      f32x4 q2[4], k2[4], v2[4], k1[4], v1[4];
      layerB<4>(zB, LW, LB_ZQ, P + PB_ZINB, q2, lane, q);
      layerB2<4>(zB, yB, LW, LB_ZK, P + PB_ZINB + 64, k2, k1, lane, q);
      layerB2<4>(zB, yB, LW, LB_ZV, P + PB_ZINB + 128, v2, v1, lane, q);

#pragma unroll
      for (int mt = 0; mt < 4; ++mt) {
        float a0 = dot4(q2[mt], k0r[mt]);
        float a1 = dot4(q2[mt], k1[mt]);
        float a2 = dot4(q2[mt], k2[mt]);
        a0 += __shfl_xor(a0, 16); a0 += __shfl_xor(a0, 32);
        a1 += __shfl_xor(a1, 16); a1 += __shfl_xor(a1, 32);
        a2 += __shfl_xor(a2, 16); a2 += __shfl_xor(a2, 32);
        a0 *= 0.25f; a1 *= 0.25f; a2 *= 0.25f;
        float mx = fmaxf(a0, fmaxf(a1, a2));
        float e0 = __expf(a0 - mx), e1 = __expf(a1 - mx), e2 = __expf(a2 - mx);
        float inv = __builtin_amdgcn_rcpf(e0 + e1 + e2);
        f32x4 o;
        o.x = (v0r[mt].x * e0 + v1[mt].x * e1 + v2[mt].x * e2) * inv;
        o.y = (v0r[mt].y * e0 + v1[mt].y * e1 + v2[mt].y * e2) * inv;
        o.z = (v0r[mt].z * e0 + v1[mt].z * e1 + v2[mt].z * e2) * inv;
        o.w = (v0r[mt].w * e0 + v1[mt].w * e1 + v2[mt].w * e2) * inv;
        stc(TH, S64, mt, q, s, o);
      }

      // z branch
      f32x4 zr[4];
      layerN<4, 2>(TH, S64, LW, LB_ZOUT, P + PB_ZOUTB, zr, lane, q, s);
#pragma unroll
      for (int mt = 0; mt < 4; ++mt) {
        zr[mt].x += zC[mt].x; zr[mt].y += zC[mt].y;
        zr[mt].z += zC[mt].z; zr[mt].w += zC[mt].w;
      }
      lnorm_c(zr, P + PB_ZN1G, P + PB_ZN1B, q);
#pragma unroll
      for (int mt = 0; mt < 4; ++mt) stc(TH, S64, mt, q, s, zr[mt]);

      f32x4 h8[8];
      layerN<8, 2>(TH, S64, LW, LB_ZF1, P + PB_ZF1B, h8, lane, q, s);
#pragma unroll
      for (int mt = 0; mt < 8; ++mt) {
        h8[mt].x = gelu1(h8[mt].x); h8[mt].y = gelu1(h8[mt].y);
        h8[mt].z = gelu1(h8[mt].z); h8[mt].w = gelu1(h8[mt].w);
        stc(TH, S128, mt, q, s, h8[mt]);
      }
      f32x4 z2[4];
      layerN<4, 4>(TH, S128, LW, LB_ZF2, P + PB_ZF2B, z2, lane, q, s);
#pragma unroll
      for (int mt = 0; mt < 4; ++mt) {
        z2[mt].x += zr[mt].x; z2[mt].y += zr[mt].y;
        z2[mt].z += zr[mt].z; z2[mt].w += zr[mt].w;
      }
      lnorm_c(z2, P + PB_ZN2G, P + PB_ZN2B, q);
#pragma unroll
      for (int mt = 0; mt < 4; ++mt) zC[mt] = z2[mt];
      c2b(z2, zB[0], zB[1], lane);

      // y branch
      f32x4 t4[4];
      layerB<4>(zB, LW, LB_YV, P + PB_YVB, t4, lane, q);
#pragma unroll
      for (int mt = 0; mt < 4; ++mt) stc(TH, S64, mt, q, s, t4[mt]);

      f32x4 yr[4];
      layerN<4, 2>(TH, S64, LW, LB_YOUT, P + PB_YOUTB, yr, lane, q, s);
#pragma unroll
      for (int mt = 0; mt < 4; ++mt) {
        yr[mt].x += yC[mt].x; yr[mt].y += yC[mt].y;
        yr[mt].z += yC[mt].z; yr[mt].w += yC[mt].w;
      }
      lnorm_c(yr, P + PB_YN1G, P + PB_YN1B, q);
#pragma unroll
      for (int mt = 0; mt < 4; ++mt) stc(TH, S64, mt, q, s, yr[mt]);

      layerN<8, 2>(TH, S64, LW, LB_YF1, P + PB_YF1B, h8, lane, q, s);
#pragma unroll
      for (int mt = 0; mt < 8; ++mt) {
        h8[mt].x = gelu1(h8[mt].x); h8[mt].y = gelu1(h8[mt].y);
        h8[mt].z = gelu1(h8[mt].z); h8[mt].w = gelu1(h8[mt].w);
        stc(TH, S128, mt, q, s, h8[mt]);
      }
      f32x4 y2[4];
      layerN<4, 4>(TH, S128, LW, LB_YF2, P + PB_YF2B, y2, lane, q, s);
#pragma unroll
      for (int mt = 0; mt < 4; ++mt) {
        y2[mt].x += yr[mt].x; y2[mt].y += yr[mt].y;
        y2[mt].z += yr[mt].z; y2[mt].w += yr[mt].w;
      }
      lnorm_c(y2, P + PB_YN2G, P + PB_YN2B, q);
#pragma unroll
      for (int mt = 0; mt < 4; ++mt) yC[mt] = y2[mt];
      c2b(y2, yB[0], yB[1], lane);
    }

    // ---- out = (y @ W_out^T + b_out)[:, 0] from registers ----
    float acc = 0.f;
#pragma unroll
    for (int mt = 0; mt < 4; ++mt) {
      f32x4 w4 = *(const f32x4*)(P + PB_WOUT + mt * 16 + q * 4);
      acc += dot4(yC[mt], w4);
    }
    acc += __shfl_xor(acc, 16); acc += __shfl_xor(acc, 32);
    if (q == 0 && (row0 + s) < p.nrows) p.out[row0 + s] = acc + P[PB_BOUT];
  }
}

extern "C" void kernel_launch(void* const* d_in, const int* in_sizes, int n_in,
                              void* d_out, int out_size, void* d_ws,
                              size_t ws_size, hipStream_t stream) {
  Params p;
  const float* const* in = (const float* const*)d_in;
  p.x        = in[0];  p.W_in     = in[1];  p.b_in     = in[2];
  p.g_in     = in[3];  p.be_in    = in[4];
  p.z_in_w   = in[5];  p.z_in_b   = in[6];
  p.z_out_w  = in[7];  p.z_out_b  = in[8];
  p.z_ffn_w1 = in[9];  p.z_ffn_b1 = in[10];
  p.z_ffn_w2 = in[11]; p.z_ffn_b2 = in[12];
  p.zn1_g    = in[13]; p.zn1_b    = in[14];
  p.zn2_g    = in[15]; p.zn2_b    = in[16];
  p.y_in_w   = in[17]; p.y_in_b   = in[18];
  p.y_out_w  = in[19]; p.y_out_b  = in[20];
  p.y_ffn_w1 = in[21]; p.y_ffn_b1 = in[22];
  p.y_ffn_w2 = in[23]; p.y_ffn_b2 = in[24];
  p.yn1_g    = in[25]; p.yn1_b    = in[26];
  p.yn2_g    = in[27]; p.yn2_b    = in[28];
  p.W_out    = in[29]; p.b_out    = in[30];
  p.out      = (float*)d_out;
  p.nrows    = in_sizes[0] / INDIM;

  if (ws_size < (size_t)NFRAG * 1024 + NPARAM * 4) return;
  ushort* wf = (ushort*)d_ws;

  hipLaunchKernelGGL(prepack_kernel, dim3(NFRAG + 1), dim3(64), 0, stream, p, wf);
  hipLaunchKernelGGL(trm_mfma_kernel, dim3(256), dim3(512), 0, stream, p, wf);
}

// Round 5
// 994.456 us; speedup vs baseline: 1.1888x; 1.1888x over previous
//
#include <hip/hip_runtime.h>
#include <math.h>

// ---------------------------------------------------------------------------
// Round 5: R4 structure, despilled.
//   - amdgpu_waves_per_eu(2) -> 256-VGPR cap (R4's launch_bounds(512,2) was
//     taken as 2 blocks/CU -> 128-VGPR cap -> 1.5 GB scratch spill traffic).
//   - Persistent carries (k0, v0, z-res, y-res) packed as bf16 pairs in uints:
//     -32 live VGPRs, same numerics as R3's LDS bf16 round-trip.
//   - Attention split: k-phase (scores+softmax) completes and frees k regs
//     before v-phase materializes v regs: -~32 peak live VGPRs.
//   - Weights+params in LDS (120.8 KB), per-wave TH scratch 4.3 KB x 8 waves,
//     512-thread blocks, 8 waves/CU = 2/SIMD.
// ---------------------------------------------------------------------------

constexpr int STEPS = 16;
constexpr int INDIM = 200;

typedef __attribute__((ext_vector_type(8))) short bfrag8;   // 8 bf16 = 4 VGPR
typedef __attribute__((ext_vector_type(4))) float f32x4;
typedef __attribute__((ext_vector_type(4))) short s16x4;

constexpr int FB_WIN  = 0;    // W_in: mt(4) x kt(7)
constexpr int NFRAG   = 140;
constexpr int NPARAM  = 1544;

// LDS-resident steady frag indices (= global index - 28)
constexpr int LB_ZQ   = 0;
constexpr int LB_ZK   = 8;
constexpr int LB_ZV   = 16;
constexpr int LB_ZOUT = 24;
constexpr int LB_ZF1  = 32;
constexpr int LB_ZF2  = 48;
constexpr int LB_YV   = 64;
constexpr int LB_YOUT = 72;
constexpr int LB_YF1  = 80;
constexpr int LB_YF2  = 96;
constexpr int NSTEADY = 112;

// packed param float offsets
constexpr int PB_BIN   = 0;
constexpr int PB_GIN   = 64;
constexpr int PB_BEIN  = 128;
constexpr int PB_ZINB  = 192;
constexpr int PB_ZOUTB = 384;
constexpr int PB_ZF1B  = 448;
constexpr int PB_ZF2B  = 576;
constexpr int PB_ZN1G  = 640;
constexpr int PB_ZN1B  = 704;
constexpr int PB_ZN2G  = 768;
constexpr int PB_ZN2B  = 832;
constexpr int PB_YVB   = 896;
constexpr int PB_YOUTB = 960;
constexpr int PB_YF1B  = 1024;
constexpr int PB_YF2B  = 1152;
constexpr int PB_YN1G  = 1216;
constexpr int PB_YN1B  = 1280;
constexpr int PB_YN2G  = 1344;
constexpr int PB_YN2B  = 1408;
constexpr int PB_WOUT  = 1472;
constexpr int PB_BOUT  = 1536;

// LDS arena layout (shorts)
constexpr int S64      = 72;
constexpr int S128     = 136;
constexpr int L_W      = 0;                       // 112 frags = 57,344 shorts
constexpr int L_P      = 57344;                   // 3,088 shorts
constexpr int L_ACT    = 60432;                   // 8 waves x TH
constexpr int WAVE_SH  = 2176;                    // TH: 16*136
constexpr int NWAVE    = 8;
constexpr int ARENA_SH = L_ACT + NWAVE * WAVE_SH; // 77,840 shorts = 155,680 B

struct Params {
  const float *x, *W_in, *b_in, *g_in, *be_in;
  const float *z_in_w, *z_in_b, *z_out_w, *z_out_b;
  const float *z_ffn_w1, *z_ffn_b1, *z_ffn_w2, *z_ffn_b2;
  const float *zn1_g, *zn1_b, *zn2_g, *zn2_b;
  const float *y_in_w, *y_in_b, *y_out_w, *y_out_b;
  const float *y_ffn_w1, *y_ffn_b1, *y_ffn_w2, *y_ffn_b2;
  const float *yn1_g, *yn1_b, *yn2_g, *yn2_b;
  const float *W_out, *b_out;
  float *out;
  int nrows;
};

__device__ __forceinline__ ushort f2bf(float f) {
  uint u = __float_as_uint(f);
  u += 0x7FFFu + ((u >> 16) & 1u);
  return (ushort)(u >> 16);
}
__device__ __forceinline__ uint pk2(float a, float b) {
  return (uint)f2bf(a) | ((uint)f2bf(b) << 16);
}
__device__ __forceinline__ float upk_lo(uint u) {
  return __uint_as_float(u << 16);
}
__device__ __forceinline__ float upk_hi(uint u) {
  return __uint_as_float(u & 0xFFFF0000u);
}
__device__ __forceinline__ float dot4(f32x4 a, f32x4 b) {
  return a.x * b.x + a.y * b.y + a.z * b.z + a.w * b.w;
}
__device__ __forceinline__ void stc(short* buf, int stride, int mt, int q,
                                    int s, f32x4 c) {
  s16x4 v;
  v.x = (short)f2bf(c.x); v.y = (short)f2bf(c.y);
  v.z = (short)f2bf(c.z); v.w = (short)f2bf(c.w);
  *(s16x4*)(buf + s * stride + mt * 16 + q * 4) = v;
}

// C-layout (packed bf16 pairs p[8]) -> 2 MFMA B-frags. Verified in R4.
__device__ __forceinline__ void c2b_p(const uint p[8], bfrag8& b0, bfrag8& b1,
                                      int lane) {
  const int srcA = (lane & 15) | ((lane & 16) << 1);  // s + 32*(q&1)
  const int srcB = srcA + 16;
  const bool odd = (lane & 32) != 0;                  // q>=2 wants mt 1,3
  uint ev0 = p[0], ev1 = p[1], ev2 = p[4], ev3 = p[5];
  uint od0 = p[2], od1 = p[3], od2 = p[6], od3 = p[7];
  uint rA0, rA1, rA2, rA3, rB0, rB1, rB2, rB3;
  {
    uint e, o;
    e = (uint)__shfl((int)ev0, srcA); o = (uint)__shfl((int)od0, srcA); rA0 = odd ? o : e;
    e = (uint)__shfl((int)ev1, srcA); o = (uint)__shfl((int)od1, srcA); rA1 = odd ? o : e;
    e = (uint)__shfl((int)ev2, srcA); o = (uint)__shfl((int)od2, srcA); rA2 = odd ? o : e;
    e = (uint)__shfl((int)ev3, srcA); o = (uint)__shfl((int)od3, srcA); rA3 = odd ? o : e;
    e = (uint)__shfl((int)ev0, srcB); o = (uint)__shfl((int)od0, srcB); rB0 = odd ? o : e;
    e = (uint)__shfl((int)ev1, srcB); o = (uint)__shfl((int)od1, srcB); rB1 = odd ? o : e;
    e = (uint)__shfl((int)ev2, srcB); o = (uint)__shfl((int)od2, srcB); rB2 = odd ? o : e;
    e = (uint)__shfl((int)ev3, srcB); o = (uint)__shfl((int)od3, srcB); rB3 = odd ? o : e;
  }
  union U { uint u[4]; bfrag8 b; };
  U u0, u1;
  u0.u[0] = rA0; u0.u[1] = rA1; u0.u[2] = rB0; u0.u[3] = rB1;
  u1.u[0] = rA2; u1.u[1] = rA3; u1.u[2] = rB2; u1.u[3] = rB3;
  b0 = u0.b; b1 = u1.b;
}
__device__ __forceinline__ void c2b(const f32x4 c[4], bfrag8& b0, bfrag8& b1,
                                    int lane) {
  uint p[8];
#pragma unroll
  for (int mt = 0; mt < 4; ++mt) {
    p[2 * mt]     = pk2(c[mt].x, c[mt].y);
    p[2 * mt + 1] = pk2(c[mt].z, c[mt].w);
  }
  c2b_p(p, b0, b1, lane);
}

// c[mt] = W * X^T + bias; B from LDS (TH scratch).
template <int MT, int KT>
__device__ __forceinline__ void layerN(const short* in, int stride,
                                       const short* lw, int fbase,
                                       const float* bias, f32x4* c,
                                       int lane, int q, int s) {
  bfrag8 bf[KT];
#pragma unroll
  for (int kt = 0; kt < KT; ++kt)
    bf[kt] = *(const bfrag8*)(in + s * stride + kt * 32 + q * 8);
#pragma unroll
  for (int mt = 0; mt < MT; ++mt)
    c[mt] = *(const f32x4*)(bias + mt * 16 + q * 4);
#pragma unroll
  for (int mt = 0; mt < MT; ++mt) {
#pragma unroll
    for (int kt = 0; kt < KT; ++kt) {
      bfrag8 af = *(const bfrag8*)(lw + (fbase + mt * KT + kt) * 512 + lane * 8);
      c[mt] = __builtin_amdgcn_mfma_f32_16x16x32_bf16(af, bf[kt], c[mt], 0, 0, 0);
    }
  }
}

// B from registers.
template <int MT>
__device__ __forceinline__ void layerB(const bfrag8* bf, const short* lw,
                                       int fbase, const float* bias, f32x4* c,
                                       int lane, int q) {
#pragma unroll
  for (int mt = 0; mt < MT; ++mt)
    c[mt] = *(const f32x4*)(bias + mt * 16 + q * 4);
#pragma unroll
  for (int mt = 0; mt < MT; ++mt) {
#pragma unroll
    for (int kt = 0; kt < 2; ++kt) {
      bfrag8 af = *(const bfrag8*)(lw + (fbase + mt * 2 + kt) * 512 + lane * 8);
      c[mt] = __builtin_amdgcn_mfma_f32_16x16x32_bf16(af, bf[kt], c[mt], 0, 0, 0);
    }
  }
}

// Two B inputs through the same weights: A-frag read once, 2 indep MFMA chains.
template <int MT>
__device__ __forceinline__ void layerB2(const bfrag8* bfA, const bfrag8* bfB,
                                        const short* lw, int fbase,
                                        const float* bias, f32x4* cA, f32x4* cB,
                                        int lane, int q) {
#pragma unroll
  for (int mt = 0; mt < MT; ++mt) {
    f32x4 b4 = *(const f32x4*)(bias + mt * 16 + q * 4);
    cA[mt] = b4; cB[mt] = b4;
  }
#pragma unroll
  for (int mt = 0; mt < MT; ++mt) {
#pragma unroll
    for (int kt = 0; kt < 2; ++kt) {
      bfrag8 af = *(const bfrag8*)(lw + (fbase + mt * 2 + kt) * 512 + lane * 8);
      cA[mt] = __builtin_amdgcn_mfma_f32_16x16x32_bf16(af, bfA[kt], cA[mt], 0, 0, 0);
      cB[mt] = __builtin_amdgcn_mfma_f32_16x16x32_bf16(af, bfB[kt], cB[mt], 0, 0, 0);
    }
  }
}

__device__ __forceinline__ void lnorm_c(f32x4 c[4], const float* g,
                                        const float* b, int q) {
  float sm = 0.f;
#pragma unroll
  for (int mt = 0; mt < 4; ++mt) sm += c[mt].x + c[mt].y + c[mt].z + c[mt].w;
  sm += __shfl_xor(sm, 16); sm += __shfl_xor(sm, 32);
  float mean = sm * (1.f / 64.f);
  float vs = 0.f;
#pragma unroll
  for (int mt = 0; mt < 4; ++mt) {
    f32x4 d = c[mt];
    d.x -= mean; d.y -= mean; d.z -= mean; d.w -= mean;
    c[mt] = d;
    vs += d.x * d.x + d.y * d.y + d.z * d.z + d.w * d.w;
  }
  vs += __shfl_xor(vs, 16); vs += __shfl_xor(vs, 32);
  float rs = rsqrtf(vs * (1.f / 64.f) + 1e-5f);
#pragma unroll
  for (int mt = 0; mt < 4; ++mt) {
    f32x4 g4 = *(const f32x4*)(g + mt * 16 + q * 4);
    f32x4 b4 = *(const f32x4*)(b + mt * 16 + q * 4);
    f32x4 v = c[mt];
    v.x = v.x * rs * g4.x + b4.x; v.y = v.y * rs * g4.y + b4.y;
    v.z = v.z * rs * g4.z + b4.z; v.w = v.w * rs * g4.w + b4.w;
    c[mt] = v;
  }
}

__device__ __forceinline__ float gelu1(float x) {
  float ax = fabsf(x) * 0.70710678118654752f;
  float t = __builtin_amdgcn_rcpf(1.0f + 0.3275911f * ax);
  float poly =
      ((((1.061405429f * t - 1.453152027f) * t + 1.421413741f) * t -
        0.284496736f) * t + 0.254829592f) * t;
  float e = __expf(-ax * ax);
  float erfv = copysignf(1.0f - poly * e, x);
  return 0.5f * x * (1.0f + erfv);
}

// ---------------------------------------------------------------------------
// prepack: weights -> A-frag bf16 order; params -> packed fp32 array
// ---------------------------------------------------------------------------
__global__ void prepack_kernel(Params p, ushort* wf) {
  int f = blockIdx.x;
  int lane = threadIdx.x;

  if (f == NFRAG) {
    float* pw = (float*)(wf + (size_t)NFRAG * 512);
    for (int t = lane; t < NPARAM; t += 64) {
      float v = 0.f;
      if      (t < 64)   v = p.b_in[t];
      else if (t < 128)  v = p.g_in[t - 64];
      else if (t < 192)  v = p.be_in[t - 128];
      else if (t < 384)  v = p.z_in_b[t - 192];
      else if (t < 448)  v = p.z_out_b[t - 384];
      else if (t < 576)  v = p.z_ffn_b1[t - 448];
      else if (t < 640)  v = p.z_ffn_b2[t - 576];
      else if (t < 704)  v = p.zn1_g[t - 640];
      else if (t < 768)  v = p.zn1_b[t - 704];
      else if (t < 832)  v = p.zn2_g[t - 768];
      else if (t < 896)  v = p.zn2_b[t - 832];
      else if (t < 960)  v = p.y_in_b[128 + t - 896];
      else if (t < 1024) v = p.y_out_b[t - 960];
      else if (t < 1152) v = p.y_ffn_b1[t - 1024];
      else if (t < 1216) v = p.y_ffn_b2[t - 1152];
      else if (t < 1280) v = p.yn1_g[t - 1216];
      else if (t < 1344) v = p.yn1_b[t - 1280];
      else if (t < 1408) v = p.yn2_g[t - 1344];
      else if (t < 1472) v = p.yn2_b[t - 1408];
      else if (t < 1536) v = p.W_out[t - 1472];
      else if (t == 1536) v = p.b_out[0];
      pw[t] = v;
    }
    return;
  }

  int q = lane >> 4, r = lane & 15;
  const float* src; int K, mt, kt, l;
  if (f < 28)        { src = p.W_in;                K = 200; mt = f / 7;  kt = f % 7; }
  else if (f < 36)   { l = f - 28;  src = p.z_in_w;            K = 64;  mt = l / 2; kt = l % 2; }
  else if (f < 44)   { l = f - 36;  src = p.z_in_w + 64 * 64;  K = 64;  mt = l / 2; kt = l % 2; }
  else if (f < 52)   { l = f - 44;  src = p.z_in_w + 128 * 64; K = 64;  mt = l / 2; kt = l % 2; }
  else if (f < 60)   { l = f - 52;  src = p.z_out_w;           K = 64;  mt = l / 2; kt = l % 2; }
  else if (f < 76)   { l = f - 60;  src = p.z_ffn_w1;          K = 64;  mt = l / 2; kt = l % 2; }
  else if (f < 92)   { l = f - 76;  src = p.z_ffn_w2;          K = 128; mt = l / 4; kt = l % 4; }
  else if (f < 100)  { l = f - 92;  src = p.y_in_w + 128 * 64; K = 64;  mt = l / 2; kt = l % 2; }
  else if (f < 108)  { l = f - 100; src = p.y_out_w;           K = 64;  mt = l / 2; kt = l % 2; }
  else if (f < 124)  { l = f - 108; src = p.y_ffn_w1;          K = 64;  mt = l / 2; kt = l % 2; }
  else               { l = f - 124; src = p.y_ffn_w2;          K = 128; mt = l / 4; kt = l % 4; }

  int row = mt * 16 + r;
  int col = kt * 32 + q * 8;
  bfrag8 o;
#pragma unroll
  for (int j = 0; j < 8; ++j) {
    int cc = col + j;
    float v = (cc < K) ? src[(size_t)row * K + cc] : 0.0f;
    o[j] = (short)f2bf(v);
  }
  *(bfrag8*)(wf + (size_t)f * 512 + lane * 8) = o;
}

// ---------------------------------------------------------------------------
// main kernel: 512 thr (8 waves) x 256 blocks; weights in LDS; acts in regs.
// waves_per_eu(2): VGPR cap 256 (NOT launch_bounds(512,2) -> 128-cap spills).
// ---------------------------------------------------------------------------
__global__ __launch_bounds__(512)
__attribute__((amdgpu_waves_per_eu(2)))
void trm_mfma_kernel(Params p, const ushort* wf) {
  __shared__ __align__(16) short arena[ARENA_SH];
  const int tid = threadIdx.x;
  const int wave = tid >> 6, lane = tid & 63;
  const int q = lane >> 4, s = lane & 15;

  // ---- stage steady weights + params into LDS (once per block) ----
  {
    const uint4* srcw = (const uint4*)(wf + (size_t)28 * 512);
    uint4* dstw = (uint4*)(arena + L_W);
    for (int i = tid; i < NSTEADY * 64; i += 512) dstw[i] = srcw[i];
    const uint4* srcp = (const uint4*)(wf + (size_t)NFRAG * 512);
    uint4* dstp = (uint4*)(arena + L_P);
    for (int i = tid; i < NPARAM / 4; i += 512) dstp[i] = srcp[i];
  }
  __syncthreads();  // the only barrier

  const short* LW = arena + L_W;
  const float* P  = (const float*)(arena + L_P);
  short* TH = arena + L_ACT + wave * WAVE_SH;

  const int chunks = (p.nrows + 127) / 128;
  for (int ic = blockIdx.x; ic < chunks; ic += gridDim.x) {
    const int row0 = ic * 128 + wave * 16;
    int row = row0 + s;
    if (row >= p.nrows) row = p.nrows - 1;

    // ---- x_proj = gelu(ln(x @ W_in^T + b_in)); stays in registers ----
    bfrag8 xpB[2];
    {
      const float* xr = p.x + (size_t)row * INDIM;
      bfrag8 xb[7];
#pragma unroll
      for (int kt = 0; kt < 7; ++kt) {
        int k0i = kt * 32 + q * 8;
        bfrag8 t;
        if (kt < 6 || q == 0) {
          f32x4 lo = *(const f32x4*)(xr + k0i);
          f32x4 hi = *(const f32x4*)(xr + k0i + 4);
          t[0] = (short)f2bf(lo.x); t[1] = (short)f2bf(lo.y);
          t[2] = (short)f2bf(lo.z); t[3] = (short)f2bf(lo.w);
          t[4] = (short)f2bf(hi.x); t[5] = (short)f2bf(hi.y);
          t[6] = (short)f2bf(hi.z); t[7] = (short)f2bf(hi.w);
        } else {
#pragma unroll
          for (int j = 0; j < 8; ++j) t[j] = 0;
        }
        xb[kt] = t;
      }
      f32x4 c[4];
#pragma unroll
      for (int mt = 0; mt < 4; ++mt)
        c[mt] = *(const f32x4*)(P + PB_BIN + mt * 16 + q * 4);
#pragma unroll
      for (int mt = 0; mt < 4; ++mt)
#pragma unroll
        for (int kt = 0; kt < 7; ++kt) {
          bfrag8 af =
              *(const bfrag8*)(wf + (size_t)(FB_WIN + mt * 7 + kt) * 512 + lane * 8);
          c[mt] = __builtin_amdgcn_mfma_f32_16x16x32_bf16(af, xb[kt], c[mt], 0, 0, 0);
        }
      lnorm_c(c, P + PB_GIN, P + PB_BEIN, q);
#pragma unroll
      for (int mt = 0; mt < 4; ++mt) {
        c[mt].x = gelu1(c[mt].x); c[mt].y = gelu1(c[mt].y);
        c[mt].z = gelu1(c[mt].z); c[mt].w = gelu1(c[mt].w);
      }
      c2b(c, xpB[0], xpB[1], lane);
    }

    // ---- k0/v0 packed bf16 in registers; zero state ----
    uint k0p[8], v0p[8], zCp[8], yCp[8];
    bfrag8 zB[2], yB[2];
    {
      f32x4 ck[4], cv[4];
      layerB<4>(xpB, LW, LB_ZK, P + PB_ZINB + 64, ck, lane, q);
      layerB<4>(xpB, LW, LB_ZV, P + PB_ZINB + 128, cv, lane, q);
#pragma unroll
      for (int mt = 0; mt < 4; ++mt) {
        k0p[2 * mt]     = pk2(ck[mt].x, ck[mt].y);
        k0p[2 * mt + 1] = pk2(ck[mt].z, ck[mt].w);
        v0p[2 * mt]     = pk2(cv[mt].x, cv[mt].y);
        v0p[2 * mt + 1] = pk2(cv[mt].z, cv[mt].w);
        zCp[2 * mt] = 0u; zCp[2 * mt + 1] = 0u;
        yCp[2 * mt] = 0u; yCp[2 * mt + 1] = 0u;
      }
#pragma unroll
      for (int kt = 0; kt < 2; ++kt) {
        bfrag8 t;
#pragma unroll
        for (int j = 0; j < 8; ++j) t[j] = 0;
        zB[kt] = t; yB[kt] = t;
      }
    }

    // ---- 16 recursive steps ----
    for (int st = 0; st < STEPS; ++st) {
      // -- attention k-phase: scores + softmax, k regs freed after --
      float w0[4], w1[4], w2[4], wi[4];
      {
        f32x4 q2[4], kz[4], ky[4];
        layerB<4>(zB, LW, LB_ZQ, P + PB_ZINB, q2, lane, q);
        layerB2<4>(zB, yB, LW, LB_ZK, P + PB_ZINB + 64, kz, ky, lane, q);
#pragma unroll
        for (int mt = 0; mt < 4; ++mt) {
          float a0 = q2[mt].x * upk_lo(k0p[2 * mt]) +
                     q2[mt].y * upk_hi(k0p[2 * mt]) +
                     q2[mt].z * upk_lo(k0p[2 * mt + 1]) +
                     q2[mt].w * upk_hi(k0p[2 * mt + 1]);
          float a1 = dot4(q2[mt], ky[mt]);
          float a2 = dot4(q2[mt], kz[mt]);
          a0 += __shfl_xor(a0, 16); a0 += __shfl_xor(a0, 32);
          a1 += __shfl_xor(a1, 16); a1 += __shfl_xor(a1, 32);
          a2 += __shfl_xor(a2, 16); a2 += __shfl_xor(a2, 32);
          a0 *= 0.25f; a1 *= 0.25f; a2 *= 0.25f;
          float mx = fmaxf(a0, fmaxf(a1, a2));
          float e0 = __expf(a0 - mx), e1 = __expf(a1 - mx), e2 = __expf(a2 - mx);
          w0[mt] = e0; w1[mt] = e1; w2[mt] = e2;
          wi[mt] = __builtin_amdgcn_rcpf(e0 + e1 + e2);
        }
      }
      // -- attention v-phase --
      {
        f32x4 vz[4], vy[4];
        layerB2<4>(zB, yB, LW, LB_ZV, P + PB_ZINB + 128, vz, vy, lane, q);
#pragma unroll
        for (int mt = 0; mt < 4; ++mt) {
          f32x4 o;
          o.x = (upk_lo(v0p[2 * mt])     * w0[mt] + vy[mt].x * w1[mt] +
                 vz[mt].x * w2[mt]) * wi[mt];
          o.y = (upk_hi(v0p[2 * mt])     * w0[mt] + vy[mt].y * w1[mt] +
                 vz[mt].y * w2[mt]) * wi[mt];
          o.z = (upk_lo(v0p[2 * mt + 1]) * w0[mt] + vy[mt].z * w1[mt] +
                 vz[mt].z * w2[mt]) * wi[mt];
          o.w = (upk_hi(v0p[2 * mt + 1]) * w0[mt] + vy[mt].w * w1[mt] +
                 vz[mt].w * w2[mt]) * wi[mt];
          stc(TH, S64, mt, q, s, o);
        }
      }

      // -- z branch --
      f32x4 zr[4];
      layerN<4, 2>(TH, S64, LW, LB_ZOUT, P + PB_ZOUTB, zr, lane, q, s);
#pragma unroll
      for (int mt = 0; mt < 4; ++mt) {
        zr[mt].x += upk_lo(zCp[2 * mt]);     zr[mt].y += upk_hi(zCp[2 * mt]);
        zr[mt].z += upk_lo(zCp[2 * mt + 1]); zr[mt].w += upk_hi(zCp[2 * mt + 1]);
      }
      lnorm_c(zr, P + PB_ZN1G, P + PB_ZN1B, q);
#pragma unroll
      for (int mt = 0; mt < 4; ++mt) stc(TH, S64, mt, q, s, zr[mt]);

      f32x4 h8[8];
      layerN<8, 2>(TH, S64, LW, LB_ZF1, P + PB_ZF1B, h8, lane, q, s);
#pragma unroll
      for (int mt = 0; mt < 8; ++mt) {
        h8[mt].x = gelu1(h8[mt].x); h8[mt].y = gelu1(h8[mt].y);
        h8[mt].z = gelu1(h8[mt].z); h8[mt].w = gelu1(h8[mt].w);
        stc(TH, S128, mt, q, s, h8[mt]);
      }
      f32x4 z2[4];
      layerN<4, 4>(TH, S128, LW, LB_ZF2, P + PB_ZF2B, z2, lane, q, s);
#pragma unroll
      for (int mt = 0; mt < 4; ++mt) {
        z2[mt].x += zr[mt].x; z2[mt].y += zr[mt].y;
        z2[mt].z += zr[mt].z; z2[mt].w += zr[mt].w;
      }
      lnorm_c(z2, P + PB_ZN2G, P + PB_ZN2B, q);
      {
        uint zp[8];
#pragma unroll
        for (int mt = 0; mt < 4; ++mt) {
          zp[2 * mt]     = pk2(z2[mt].x, z2[mt].y);
          zp[2 * mt + 1] = pk2(z2[mt].z, z2[mt].w);
          zCp[2 * mt] = zp[2 * mt]; zCp[2 * mt + 1] = zp[2 * mt + 1];
        }
        c2b_p(zp, zB[0], zB[1], lane);
      }

      // -- y branch --
      f32x4 t4[4];
      layerB<4>(zB, LW, LB_YV, P + PB_YVB, t4, lane, q);
#pragma unroll
      for (int mt = 0; mt < 4; ++mt) stc(TH, S64, mt, q, s, t4[mt]);

      f32x4 yr[4];
      layerN<4, 2>(TH, S64, LW, LB_YOUT, P + PB_YOUTB, yr, lane, q, s);
#pragma unroll
      for (int mt = 0; mt < 4; ++mt) {
        yr[mt].x += upk_lo(yCp[2 * mt]);     yr[mt].y += upk_hi(yCp[2 * mt]);
        yr[mt].z += upk_lo(yCp[2 * mt + 1]); yr[mt].w += upk_hi(yCp[2 * mt + 1]);
      }
      lnorm_c(yr, P + PB_YN1G, P + PB_YN1B, q);
#pragma unroll
      for (int mt = 0; mt < 4; ++mt) stc(TH, S64, mt, q, s, yr[mt]);

      layerN<8, 2>(TH, S64, LW, LB_YF1, P + PB_YF1B, h8, lane, q, s);
#pragma unroll
      for (int mt = 0; mt < 8; ++mt) {
        h8[mt].x = gelu1(h8[mt].x); h8[mt].y = gelu1(h8[mt].y);
        h8[mt].z = gelu1(h8[mt].z); h8[mt].w = gelu1(h8[mt].w);
        stc(TH, S128, mt, q, s, h8[mt]);
      }
      f32x4 y2[4];
      layerN<4, 4>(TH, S128, LW, LB_YF2, P + PB_YF2B, y2, lane, q, s);
#pragma unroll
      for (int mt = 0; mt < 4; ++mt) {
        y2[mt].x += yr[mt].x; y2[mt].y += yr[mt].y;
        y2[mt].z += yr[mt].z; y2[mt].w += yr[mt].w;
      }
      lnorm_c(y2, P + PB_YN2G, P + PB_YN2B, q);
      {
        uint yp[8];
#pragma unroll
        for (int mt = 0; mt < 4; ++mt) {
          yp[2 * mt]     = pk2(y2[mt].x, y2[mt].y);
          yp[2 * mt + 1] = pk2(y2[mt].z, y2[mt].w);
          yCp[2 * mt] = yp[2 * mt]; yCp[2 * mt + 1] = yp[2 * mt + 1];
        }
        c2b_p(yp, yB[0], yB[1], lane);
      }
    }

    // ---- out = (y @ W_out^T + b_out)[:, 0] from packed carry ----
    float acc = 0.f;
#pragma unroll
    for (int mt = 0; mt < 4; ++mt) {
      f32x4 w4 = *(const f32x4*)(P + PB_WOUT + mt * 16 + q * 4);
      acc += upk_lo(yCp[2 * mt]) * w4.x + upk_hi(yCp[2 * mt]) * w4.y +
             upk_lo(yCp[2 * mt + 1]) * w4.z + upk_hi(yCp[2 * mt + 1]) * w4.w;
    }
    acc += __shfl_xor(acc, 16); acc += __shfl_xor(acc, 32);
    if (q == 0 && (row0 + s) < p.nrows) p.out[row0 + s] = acc + P[PB_BOUT];
  }
}

extern "C" void kernel_launch(void* const* d_in, const int* in_sizes, int n_in,
                              void* d_out, int out_size, void* d_ws,
                              size_t ws_size, hipStream_t stream) {
  Params p;
  const float* const* in = (const float* const*)d_in;
  p.x        = in[0];  p.W_in     = in[1];  p.b_in     = in[2];
  p.g_in     = in[3];  p.be_in    = in[4];
  p.z_in_w   = in[5];  p.z_in_b   = in[6];
  p.z_out_w  = in[7];  p.z_out_b  = in[8];
  p.z_ffn_w1 = in[9];  p.z_ffn_b1 = in[10];
  p.z_ffn_w2 = in[11]; p.z_ffn_b2 = in[12];
  p.zn1_g    = in[13]; p.zn1_b    = in[14];
  p.zn2_g    = in[15]; p.zn2_b    = in[16];
  p.y_in_w   = in[17]; p.y_in_b   = in[18];
  p.y_out_w  = in[19]; p.y_out_b  = in[20];
  p.y_ffn_w1 = in[21]; p.y_ffn_b1 = in[22];
  p.y_ffn_w2 = in[23]; p.y_ffn_b2 = in[24];
  p.yn1_g    = in[25]; p.yn1_b    = in[26];
  p.yn2_g    = in[27]; p.yn2_b    = in[28];
  p.W_out    = in[29]; p.b_out    = in[30];
  p.out      = (float*)d_out;
  p.nrows    = in_sizes[0] / INDIM;

  if (ws_size < (size_t)NFRAG * 1024 + NPARAM * 4) return;
  ushort* wf = (ushort*)d_ws;

  hipLaunchKernelGGL(prepack_kernel, dim3(NFRAG + 1), dim3(64), 0, stream, p, wf);
  hipLaunchKernelGGL(trm_mfma_kernel, dim3(256), dim3(512), 0, stream, p, wf);
}

// Round 6
// 989.098 us; speedup vs baseline: 1.1953x; 1.0054x over previous
//
#include <hip/hip_runtime.h>
#include <math.h>

// ---------------------------------------------------------------------------
// Round 6: despill for real.
//   - amdgpu_flat_work_group_size(512,512) + amdgpu_waves_per_eu(2,2):
//     pins allocator target to exactly 2 waves/EU -> 256-VGPR budget.
//     (R5's waves_per_eu(2) set only the MIN; allocator still chose 128 and
//      spilled ~550 MB of scratch traffic.)
//   - LN1 residuals zr/yr packed to bf16 pairs right after the FFN-input
//     store: ~16 fewer peak live VGPRs (insurance if the attr underdelivers).
//   - Everything else identical to R5.
// ---------------------------------------------------------------------------

constexpr int STEPS = 16;
constexpr int INDIM = 200;

typedef __attribute__((ext_vector_type(8))) short bfrag8;   // 8 bf16 = 4 VGPR
typedef __attribute__((ext_vector_type(4))) float f32x4;
typedef __attribute__((ext_vector_type(4))) short s16x4;

constexpr int FB_WIN  = 0;    // W_in: mt(4) x kt(7)
constexpr int NFRAG   = 140;
constexpr int NPARAM  = 1544;

// LDS-resident steady frag indices (= global index - 28)
constexpr int LB_ZQ   = 0;
constexpr int LB_ZK   = 8;
constexpr int LB_ZV   = 16;
constexpr int LB_ZOUT = 24;
constexpr int LB_ZF1  = 32;
constexpr int LB_ZF2  = 48;
constexpr int LB_YV   = 64;
constexpr int LB_YOUT = 72;
constexpr int LB_YF1  = 80;
constexpr int LB_YF2  = 96;
constexpr int NSTEADY = 112;

// packed param float offsets
constexpr int PB_BIN   = 0;
constexpr int PB_GIN   = 64;
constexpr int PB_BEIN  = 128;
constexpr int PB_ZINB  = 192;
constexpr int PB_ZOUTB = 384;
constexpr int PB_ZF1B  = 448;
constexpr int PB_ZF2B  = 576;
constexpr int PB_ZN1G  = 640;
constexpr int PB_ZN1B  = 704;
constexpr int PB_ZN2G  = 768;
constexpr int PB_ZN2B  = 832;
constexpr int PB_YVB   = 896;
constexpr int PB_YOUTB = 960;
constexpr int PB_YF1B  = 1024;
constexpr int PB_YF2B  = 1152;
constexpr int PB_YN1G  = 1216;
constexpr int PB_YN1B  = 1280;
constexpr int PB_YN2G  = 1344;
constexpr int PB_YN2B  = 1408;
constexpr int PB_WOUT  = 1472;
constexpr int PB_BOUT  = 1536;

// LDS arena layout (shorts)
constexpr int S64      = 72;
constexpr int S128     = 136;
constexpr int L_W      = 0;                       // 112 frags = 57,344 shorts
constexpr int L_P      = 57344;                   // 3,088 shorts
constexpr int L_ACT    = 60432;                   // 8 waves x TH
constexpr int WAVE_SH  = 2176;                    // TH: 16*136
constexpr int NWAVE    = 8;
constexpr int ARENA_SH = L_ACT + NWAVE * WAVE_SH; // 77,840 shorts = 155,680 B

struct Params {
  const float *x, *W_in, *b_in, *g_in, *be_in;
  const float *z_in_w, *z_in_b, *z_out_w, *z_out_b;
  const float *z_ffn_w1, *z_ffn_b1, *z_ffn_w2, *z_ffn_b2;
  const float *zn1_g, *zn1_b, *zn2_g, *zn2_b;
  const float *y_in_w, *y_in_b, *y_out_w, *y_out_b;
  const float *y_ffn_w1, *y_ffn_b1, *y_ffn_w2, *y_ffn_b2;
  const float *yn1_g, *yn1_b, *yn2_g, *yn2_b;
  const float *W_out, *b_out;
  float *out;
  int nrows;
};

__device__ __forceinline__ ushort f2bf(float f) {
  uint u = __float_as_uint(f);
  u += 0x7FFFu + ((u >> 16) & 1u);
  return (ushort)(u >> 16);
}
__device__ __forceinline__ uint pk2(float a, float b) {
  return (uint)f2bf(a) | ((uint)f2bf(b) << 16);
}
__device__ __forceinline__ float upk_lo(uint u) {
  return __uint_as_float(u << 16);
}
__device__ __forceinline__ float upk_hi(uint u) {
  return __uint_as_float(u & 0xFFFF0000u);
}
__device__ __forceinline__ float dot4(f32x4 a, f32x4 b) {
  return a.x * b.x + a.y * b.y + a.z * b.z + a.w * b.w;
}
__device__ __forceinline__ void stc(short* buf, int stride, int mt, int q,
                                    int s, f32x4 c) {
  s16x4 v;
  v.x = (short)f2bf(c.x); v.y = (short)f2bf(c.y);
  v.z = (short)f2bf(c.z); v.w = (short)f2bf(c.w);
  *(s16x4*)(buf + s * stride + mt * 16 + q * 4) = v;
}

// C-layout (packed bf16 pairs p[8]) -> 2 MFMA B-frags. Verified in R4.
__device__ __forceinline__ void c2b_p(const uint p[8], bfrag8& b0, bfrag8& b1,
                                      int lane) {
  const int srcA = (lane & 15) | ((lane & 16) << 1);  // s + 32*(q&1)
  const int srcB = srcA + 16;
  const bool odd = (lane & 32) != 0;                  // q>=2 wants mt 1,3
  uint ev0 = p[0], ev1 = p[1], ev2 = p[4], ev3 = p[5];
  uint od0 = p[2], od1 = p[3], od2 = p[6], od3 = p[7];
  uint rA0, rA1, rA2, rA3, rB0, rB1, rB2, rB3;
  {
    uint e, o;
    e = (uint)__shfl((int)ev0, srcA); o = (uint)__shfl((int)od0, srcA); rA0 = odd ? o : e;
    e = (uint)__shfl((int)ev1, srcA); o = (uint)__shfl((int)od1, srcA); rA1 = odd ? o : e;
    e = (uint)__shfl((int)ev2, srcA); o = (uint)__shfl((int)od2, srcA); rA2 = odd ? o : e;
    e = (uint)__shfl((int)ev3, srcA); o = (uint)__shfl((int)od3, srcA); rA3 = odd ? o : e;
    e = (uint)__shfl((int)ev0, srcB); o = (uint)__shfl((int)od0, srcB); rB0 = odd ? o : e;
    e = (uint)__shfl((int)ev1, srcB); o = (uint)__shfl((int)od1, srcB); rB1 = odd ? o : e;
    e = (uint)__shfl((int)ev2, srcB); o = (uint)__shfl((int)od2, srcB); rB2 = odd ? o : e;
    e = (uint)__shfl((int)ev3, srcB); o = (uint)__shfl((int)od3, srcB); rB3 = odd ? o : e;
  }
  union U { uint u[4]; bfrag8 b; };
  U u0, u1;
  u0.u[0] = rA0; u0.u[1] = rA1; u0.u[2] = rB0; u0.u[3] = rB1;
  u1.u[0] = rA2; u1.u[1] = rA3; u1.u[2] = rB2; u1.u[3] = rB3;
  b0 = u0.b; b1 = u1.b;
}
__device__ __forceinline__ void c2b(const f32x4 c[4], bfrag8& b0, bfrag8& b1,
                                    int lane) {
  uint p[8];
#pragma unroll
  for (int mt = 0; mt < 4; ++mt) {
    p[2 * mt]     = pk2(c[mt].x, c[mt].y);
    p[2 * mt + 1] = pk2(c[mt].z, c[mt].w);
  }
  c2b_p(p, b0, b1, lane);
}

// c[mt] = W * X^T + bias; B from LDS (TH scratch).
template <int MT, int KT>
__device__ __forceinline__ void layerN(const short* in, int stride,
                                       const short* lw, int fbase,
                                       const float* bias, f32x4* c,
                                       int lane, int q, int s) {
  bfrag8 bf[KT];
#pragma unroll
  for (int kt = 0; kt < KT; ++kt)
    bf[kt] = *(const bfrag8*)(in + s * stride + kt * 32 + q * 8);
#pragma unroll
  for (int mt = 0; mt < MT; ++mt)
    c[mt] = *(const f32x4*)(bias + mt * 16 + q * 4);
#pragma unroll
  for (int mt = 0; mt < MT; ++mt) {
#pragma unroll
    for (int kt = 0; kt < KT; ++kt) {
      bfrag8 af = *(const bfrag8*)(lw + (fbase + mt * KT + kt) * 512 + lane * 8);
      c[mt] = __builtin_amdgcn_mfma_f32_16x16x32_bf16(af, bf[kt], c[mt], 0, 0, 0);
    }
  }
}

// B from registers.
template <int MT>
__device__ __forceinline__ void layerB(const bfrag8* bf, const short* lw,
                                       int fbase, const float* bias, f32x4* c,
                                       int lane, int q) {
#pragma unroll
  for (int mt = 0; mt < MT; ++mt)
    c[mt] = *(const f32x4*)(bias + mt * 16 + q * 4);
#pragma unroll
  for (int mt = 0; mt < MT; ++mt) {
#pragma unroll
    for (int kt = 0; kt < 2; ++kt) {
      bfrag8 af = *(const bfrag8*)(lw + (fbase + mt * 2 + kt) * 512 + lane * 8);
      c[mt] = __builtin_amdgcn_mfma_f32_16x16x32_bf16(af, bf[kt], c[mt], 0, 0, 0);
    }
  }
}

// Two B inputs through the same weights: A-frag read once, 2 indep MFMA chains.
template <int MT>
__device__ __forceinline__ void layerB2(const bfrag8* bfA, const bfrag8* bfB,
                                        const short* lw, int fbase,
                                        const float* bias, f32x4* cA, f32x4* cB,
                                        int lane, int q) {
#pragma unroll
  for (int mt = 0; mt < MT; ++mt) {
    f32x4 b4 = *(const f32x4*)(bias + mt * 16 + q * 4);
    cA[mt] = b4; cB[mt] = b4;
  }
#pragma unroll
  for (int mt = 0; mt < MT; ++mt) {
#pragma unroll
    for (int kt = 0; kt < 2; ++kt) {
      bfrag8 af = *(const bfrag8*)(lw + (fbase + mt * 2 + kt) * 512 + lane * 8);
      cA[mt] = __builtin_amdgcn_mfma_f32_16x16x32_bf16(af, bfA[kt], cA[mt], 0, 0, 0);
      cB[mt] = __builtin_amdgcn_mfma_f32_16x16x32_bf16(af, bfB[kt], cB[mt], 0, 0, 0);
    }
  }
}

__device__ __forceinline__ void lnorm_c(f32x4 c[4], const float* g,
                                        const float* b, int q) {
  float sm = 0.f;
#pragma unroll
  for (int mt = 0; mt < 4; ++mt) sm += c[mt].x + c[mt].y + c[mt].z + c[mt].w;
  sm += __shfl_xor(sm, 16); sm += __shfl_xor(sm, 32);
  float mean = sm * (1.f / 64.f);
  float vs = 0.f;
#pragma unroll
  for (int mt = 0; mt < 4; ++mt) {
    f32x4 d = c[mt];
    d.x -= mean; d.y -= mean; d.z -= mean; d.w -= mean;
    c[mt] = d;
    vs += d.x * d.x + d.y * d.y + d.z * d.z + d.w * d.w;
  }
  vs += __shfl_xor(vs, 16); vs += __shfl_xor(vs, 32);
  float rs = rsqrtf(vs * (1.f / 64.f) + 1e-5f);
#pragma unroll
  for (int mt = 0; mt < 4; ++mt) {
    f32x4 g4 = *(const f32x4*)(g + mt * 16 + q * 4);
    f32x4 b4 = *(const f32x4*)(b + mt * 16 + q * 4);
    f32x4 v = c[mt];
    v.x = v.x * rs * g4.x + b4.x; v.y = v.y * rs * g4.y + b4.y;
    v.z = v.z * rs * g4.z + b4.z; v.w = v.w * rs * g4.w + b4.w;
    c[mt] = v;
  }
}

__device__ __forceinline__ float gelu1(float x) {
  float ax = fabsf(x) * 0.70710678118654752f;
  float t = __builtin_amdgcn_rcpf(1.0f + 0.3275911f * ax);
  float poly =
      ((((1.061405429f * t - 1.453152027f) * t + 1.421413741f) * t -
        0.284496736f) * t + 0.254829592f) * t;
  float e = __expf(-ax * ax);
  float erfv = copysignf(1.0f - poly * e, x);
  return 0.5f * x * (1.0f + erfv);
}

// ---------------------------------------------------------------------------
// prepack: weights -> A-frag bf16 order; params -> packed fp32 array
// ---------------------------------------------------------------------------
__global__ void prepack_kernel(Params p, ushort* wf) {
  int f = blockIdx.x;
  int lane = threadIdx.x;

  if (f == NFRAG) {
    float* pw = (float*)(wf + (size_t)NFRAG * 512);
    for (int t = lane; t < NPARAM; t += 64) {
      float v = 0.f;
      if      (t < 64)   v = p.b_in[t];
      else if (t < 128)  v = p.g_in[t - 64];
      else if (t < 192)  v = p.be_in[t - 128];
      else if (t < 384)  v = p.z_in_b[t - 192];
      else if (t < 448)  v = p.z_out_b[t - 384];
      else if (t < 576)  v = p.z_ffn_b1[t - 448];
      else if (t < 640)  v = p.z_ffn_b2[t - 576];
      else if (t < 704)  v = p.zn1_g[t - 640];
      else if (t < 768)  v = p.zn1_b[t - 704];
      else if (t < 832)  v = p.zn2_g[t - 768];
      else if (t < 896)  v = p.zn2_b[t - 832];
      else if (t < 960)  v = p.y_in_b[128 + t - 896];
      else if (t < 1024) v = p.y_out_b[t - 960];
      else if (t < 1152) v = p.y_ffn_b1[t - 1024];
      else if (t < 1216) v = p.y_ffn_b2[t - 1152];
      else if (t < 1280) v = p.yn1_g[t - 1216];
      else if (t < 1344) v = p.yn1_b[t - 1280];
      else if (t < 1408) v = p.yn2_g[t - 1344];
      else if (t < 1472) v = p.yn2_b[t - 1408];
      else if (t < 1536) v = p.W_out[t - 1472];
      else if (t == 1536) v = p.b_out[0];
      pw[t] = v;
    }
    return;
  }

  int q = lane >> 4, r = lane & 15;
  const float* src; int K, mt, kt, l;
  if (f < 28)        { src = p.W_in;                K = 200; mt = f / 7;  kt = f % 7; }
  else if (f < 36)   { l = f - 28;  src = p.z_in_w;            K = 64;  mt = l / 2; kt = l % 2; }
  else if (f < 44)   { l = f - 36;  src = p.z_in_w + 64 * 64;  K = 64;  mt = l / 2; kt = l % 2; }
  else if (f < 52)   { l = f - 44;  src = p.z_in_w + 128 * 64; K = 64;  mt = l / 2; kt = l % 2; }
  else if (f < 60)   { l = f - 52;  src = p.z_out_w;           K = 64;  mt = l / 2; kt = l % 2; }
  else if (f < 76)   { l = f - 60;  src = p.z_ffn_w1;          K = 64;  mt = l / 2; kt = l % 2; }
  else if (f < 92)   { l = f - 76;  src = p.z_ffn_w2;          K = 128; mt = l / 4; kt = l % 4; }
  else if (f < 100)  { l = f - 92;  src = p.y_in_w + 128 * 64; K = 64;  mt = l / 2; kt = l % 2; }
  else if (f < 108)  { l = f - 100; src = p.y_out_w;           K = 64;  mt = l / 2; kt = l % 2; }
  else if (f < 124)  { l = f - 108; src = p.y_ffn_w1;          K = 64;  mt = l / 2; kt = l % 2; }
  else               { l = f - 124; src = p.y_ffn_w2;          K = 128; mt = l / 4; kt = l % 4; }

  int row = mt * 16 + r;
  int col = kt * 32 + q * 8;
  bfrag8 o;
#pragma unroll
  for (int j = 0; j < 8; ++j) {
    int cc = col + j;
    float v = (cc < K) ? src[(size_t)row * K + cc] : 0.0f;
    o[j] = (short)f2bf(v);
  }
  *(bfrag8*)(wf + (size_t)f * 512 + lane * 8) = o;
}

// ---------------------------------------------------------------------------
// main kernel: 512 thr (8 waves) x 256 blocks; weights in LDS; acts in regs.
// flat_work_group_size(512,512) + waves_per_eu(2,2): allocator pinned to
// exactly 2 waves/EU -> full 256-VGPR budget, no spill.
// ---------------------------------------------------------------------------
__global__
__attribute__((amdgpu_flat_work_group_size(512, 512), amdgpu_waves_per_eu(2, 2)))
void trm_mfma_kernel(Params p, const ushort* wf) {
  __shared__ __align__(16) short arena[ARENA_SH];
  const int tid = threadIdx.x;
  const int wave = tid >> 6, lane = tid & 63;
  const int q = lane >> 4, s = lane & 15;

  // ---- stage steady weights + params into LDS (once per block) ----
  {
    const uint4* srcw = (const uint4*)(wf + (size_t)28 * 512);
    uint4* dstw = (uint4*)(arena + L_W);
    for (int i = tid; i < NSTEADY * 64; i += 512) dstw[i] = srcw[i];
    const uint4* srcp = (const uint4*)(wf + (size_t)NFRAG * 512);
    uint4* dstp = (uint4*)(arena + L_P);
    for (int i = tid; i < NPARAM / 4; i += 512) dstp[i] = srcp[i];
  }
  __syncthreads();  // the only barrier

  const short* LW = arena + L_W;
  const float* P  = (const float*)(arena + L_P);
  short* TH = arena + L_ACT + wave * WAVE_SH;

  const int chunks = (p.nrows + 127) / 128;
  for (int ic = blockIdx.x; ic < chunks; ic += gridDim.x) {
    const int row0 = ic * 128 + wave * 16;
    int row = row0 + s;
    if (row >= p.nrows) row = p.nrows - 1;

    // ---- x_proj = gelu(ln(x @ W_in^T + b_in)); stays in registers ----
    bfrag8 xpB[2];
    {
      const float* xr = p.x + (size_t)row * INDIM;
      bfrag8 xb[7];
#pragma unroll
      for (int kt = 0; kt < 7; ++kt) {
        int k0i = kt * 32 + q * 8;
        bfrag8 t;
        if (kt < 6 || q == 0) {
          f32x4 lo = *(const f32x4*)(xr + k0i);
          f32x4 hi = *(const f32x4*)(xr + k0i + 4);
          t[0] = (short)f2bf(lo.x); t[1] = (short)f2bf(lo.y);
          t[2] = (short)f2bf(lo.z); t[3] = (short)f2bf(lo.w);
          t[4] = (short)f2bf(hi.x); t[5] = (short)f2bf(hi.y);
          t[6] = (short)f2bf(hi.z); t[7] = (short)f2bf(hi.w);
        } else {
#pragma unroll
          for (int j = 0; j < 8; ++j) t[j] = 0;
        }
        xb[kt] = t;
      }
      f32x4 c[4];
#pragma unroll
      for (int mt = 0; mt < 4; ++mt)
        c[mt] = *(const f32x4*)(P + PB_BIN + mt * 16 + q * 4);
#pragma unroll
      for (int mt = 0; mt < 4; ++mt)
#pragma unroll
        for (int kt = 0; kt < 7; ++kt) {
          bfrag8 af =
              *(const bfrag8*)(wf + (size_t)(FB_WIN + mt * 7 + kt) * 512 + lane * 8);
          c[mt] = __builtin_amdgcn_mfma_f32_16x16x32_bf16(af, xb[kt], c[mt], 0, 0, 0);
        }
      lnorm_c(c, P + PB_GIN, P + PB_BEIN, q);
#pragma unroll
      for (int mt = 0; mt < 4; ++mt) {
        c[mt].x = gelu1(c[mt].x); c[mt].y = gelu1(c[mt].y);
        c[mt].z = gelu1(c[mt].z); c[mt].w = gelu1(c[mt].w);
      }
      c2b(c, xpB[0], xpB[1], lane);
    }

    // ---- k0/v0 packed bf16 in registers; zero state ----
    uint k0p[8], v0p[8], zCp[8], yCp[8];
    bfrag8 zB[2], yB[2];
    {
      f32x4 ck[4], cv[4];
      layerB<4>(xpB, LW, LB_ZK, P + PB_ZINB + 64, ck, lane, q);
      layerB<4>(xpB, LW, LB_ZV, P + PB_ZINB + 128, cv, lane, q);
#pragma unroll
      for (int mt = 0; mt < 4; ++mt) {
        k0p[2 * mt]     = pk2(ck[mt].x, ck[mt].y);
        k0p[2 * mt + 1] = pk2(ck[mt].z, ck[mt].w);
        v0p[2 * mt]     = pk2(cv[mt].x, cv[mt].y);
        v0p[2 * mt + 1] = pk2(cv[mt].z, cv[mt].w);
        zCp[2 * mt] = 0u; zCp[2 * mt + 1] = 0u;
        yCp[2 * mt] = 0u; yCp[2 * mt + 1] = 0u;
      }
#pragma unroll
      for (int kt = 0; kt < 2; ++kt) {
        bfrag8 t;
#pragma unroll
        for (int j = 0; j < 8; ++j) t[j] = 0;
        zB[kt] = t; yB[kt] = t;
      }
    }

    // ---- 16 recursive steps ----
    for (int st = 0; st < STEPS; ++st) {
      // -- attention k-phase: scores + softmax, k regs freed after --
      float w0[4], w1[4], w2[4], wi[4];
      {
        f32x4 q2[4], kz[4], ky[4];
        layerB<4>(zB, LW, LB_ZQ, P + PB_ZINB, q2, lane, q);
        layerB2<4>(zB, yB, LW, LB_ZK, P + PB_ZINB + 64, kz, ky, lane, q);
#pragma unroll
        for (int mt = 0; mt < 4; ++mt) {
          float a0 = q2[mt].x * upk_lo(k0p[2 * mt]) +
                     q2[mt].y * upk_hi(k0p[2 * mt]) +
                     q2[mt].z * upk_lo(k0p[2 * mt + 1]) +
                     q2[mt].w * upk_hi(k0p[2 * mt + 1]);
          float a1 = dot4(q2[mt], ky[mt]);
          float a2 = dot4(q2[mt], kz[mt]);
          a0 += __shfl_xor(a0, 16); a0 += __shfl_xor(a0, 32);
          a1 += __shfl_xor(a1, 16); a1 += __shfl_xor(a1, 32);
          a2 += __shfl_xor(a2, 16); a2 += __shfl_xor(a2, 32);
          a0 *= 0.25f; a1 *= 0.25f; a2 *= 0.25f;
          float mx = fmaxf(a0, fmaxf(a1, a2));
          float e0 = __expf(a0 - mx), e1 = __expf(a1 - mx), e2 = __expf(a2 - mx);
          w0[mt] = e0; w1[mt] = e1; w2[mt] = e2;
          wi[mt] = __builtin_amdgcn_rcpf(e0 + e1 + e2);
        }
      }
      // -- attention v-phase --
      {
        f32x4 vz[4], vy[4];
        layerB2<4>(zB, yB, LW, LB_ZV, P + PB_ZINB + 128, vz, vy, lane, q);
#pragma unroll
        for (int mt = 0; mt < 4; ++mt) {
          f32x4 o;
          o.x = (upk_lo(v0p[2 * mt])     * w0[mt] + vy[mt].x * w1[mt] +
                 vz[mt].x * w2[mt]) * wi[mt];
          o.y = (upk_hi(v0p[2 * mt])     * w0[mt] + vy[mt].y * w1[mt] +
                 vz[mt].y * w2[mt]) * wi[mt];
          o.z = (upk_lo(v0p[2 * mt + 1]) * w0[mt] + vy[mt].z * w1[mt] +
                 vz[mt].z * w2[mt]) * wi[mt];
          o.w = (upk_hi(v0p[2 * mt + 1]) * w0[mt] + vy[mt].w * w1[mt] +
                 vz[mt].w * w2[mt]) * wi[mt];
          stc(TH, S64, mt, q, s, o);
        }
      }

      // -- z branch --
      uint zrp[8];
      {
        f32x4 zr[4];
        layerN<4, 2>(TH, S64, LW, LB_ZOUT, P + PB_ZOUTB, zr, lane, q, s);
#pragma unroll
        for (int mt = 0; mt < 4; ++mt) {
          zr[mt].x += upk_lo(zCp[2 * mt]);     zr[mt].y += upk_hi(zCp[2 * mt]);
          zr[mt].z += upk_lo(zCp[2 * mt + 1]); zr[mt].w += upk_hi(zCp[2 * mt + 1]);
        }
        lnorm_c(zr, P + PB_ZN1G, P + PB_ZN1B, q);
#pragma unroll
        for (int mt = 0; mt < 4; ++mt) {
          stc(TH, S64, mt, q, s, zr[mt]);
          zrp[2 * mt]     = pk2(zr[mt].x, zr[mt].y);
          zrp[2 * mt + 1] = pk2(zr[mt].z, zr[mt].w);
        }
      }

      f32x4 h8[8];
      layerN<8, 2>(TH, S64, LW, LB_ZF1, P + PB_ZF1B, h8, lane, q, s);
#pragma unroll
      for (int mt = 0; mt < 8; ++mt) {
        h8[mt].x = gelu1(h8[mt].x); h8[mt].y = gelu1(h8[mt].y);
        h8[mt].z = gelu1(h8[mt].z); h8[mt].w = gelu1(h8[mt].w);
        stc(TH, S128, mt, q, s, h8[mt]);
      }
      f32x4 z2[4];
      layerN<4, 4>(TH, S128, LW, LB_ZF2, P + PB_ZF2B, z2, lane, q, s);
#pragma unroll
      for (int mt = 0; mt < 4; ++mt) {
        z2[mt].x += upk_lo(zrp[2 * mt]);     z2[mt].y += upk_hi(zrp[2 * mt]);
        z2[mt].z += upk_lo(zrp[2 * mt + 1]); z2[mt].w += upk_hi(zrp[2 * mt + 1]);
      }
      lnorm_c(z2, P + PB_ZN2G, P + PB_ZN2B, q);
      {
        uint zp[8];
#pragma unroll
        for (int mt = 0; mt < 4; ++mt) {
          zp[2 * mt]     = pk2(z2[mt].x, z2[mt].y);
          zp[2 * mt + 1] = pk2(z2[mt].z, z2[mt].w);
          zCp[2 * mt] = zp[2 * mt]; zCp[2 * mt + 1] = zp[2 * mt + 1];
        }
        c2b_p(zp, zB[0], zB[1], lane);
      }

      // -- y branch --
      f32x4 t4[4];
      layerB<4>(zB, LW, LB_YV, P + PB_YVB, t4, lane, q);
#pragma unroll
      for (int mt = 0; mt < 4; ++mt) stc(TH, S64, mt, q, s, t4[mt]);

      uint yrp[8];
      {
        f32x4 yr[4];
        layerN<4, 2>(TH, S64, LW, LB_YOUT, P + PB_YOUTB, yr, lane, q, s);
#pragma unroll
        for (int mt = 0; mt < 4; ++mt) {
          yr[mt].x += upk_lo(yCp[2 * mt]);     yr[mt].y += upk_hi(yCp[2 * mt]);
          yr[mt].z += upk_lo(yCp[2 * mt + 1]); yr[mt].w += upk_hi(yCp[2 * mt + 1]);
        }
        lnorm_c(yr, P + PB_YN1G, P + PB_YN1B, q);
#pragma unroll
        for (int mt = 0; mt < 4; ++mt) {
          stc(TH, S64, mt, q, s, yr[mt]);
          yrp[2 * mt]     = pk2(yr[mt].x, yr[mt].y);
          yrp[2 * mt + 1] = pk2(yr[mt].z, yr[mt].w);
        }
      }

      layerN<8, 2>(TH, S64, LW, LB_YF1, P + PB_YF1B, h8, lane, q, s);
#pragma unroll
      for (int mt = 0; mt < 8; ++mt) {
        h8[mt].x = gelu1(h8[mt].x); h8[mt].y = gelu1(h8[mt].y);
        h8[mt].z = gelu1(h8[mt].z); h8[mt].w = gelu1(h8[mt].w);
        stc(TH, S128, mt, q, s, h8[mt]);
      }
      f32x4 y2[4];
      layerN<4, 4>(TH, S128, LW, LB_YF2, P + PB_YF2B, y2, lane, q, s);
#pragma unroll
      for (int mt = 0; mt < 4; ++mt) {
        y2[mt].x += upk_lo(yrp[2 * mt]);     y2[mt].y += upk_hi(yrp[2 * mt]);
        y2[mt].z += upk_lo(yrp[2 * mt + 1]); y2[mt].w += upk_hi(yrp[2 * mt + 1]);
      }
      lnorm_c(y2, P + PB_YN2G, P + PB_YN2B, q);
      {
        uint yp[8];
#pragma unroll
        for (int mt = 0; mt < 4; ++mt) {
          yp[2 * mt]     = pk2(y2[mt].x, y2[mt].y);
          yp[2 * mt + 1] = pk2(y2[mt].z, y2[mt].w);
          yCp[2 * mt] = yp[2 * mt]; yCp[2 * mt + 1] = yp[2 * mt + 1];
        }
        c2b_p(yp, yB[0], yB[1], lane);
      }
    }

    // ---- out = (y @ W_out^T + b_out)[:, 0] from packed carry ----
    float acc = 0.f;
#pragma unroll
    for (int mt = 0; mt < 4; ++mt) {
      f32x4 w4 = *(const f32x4*)(P + PB_WOUT + mt * 16 + q * 4);
      acc += upk_lo(yCp[2 * mt]) * w4.x + upk_hi(yCp[2 * mt]) * w4.y +
             upk_lo(yCp[2 * mt + 1]) * w4.z + upk_hi(yCp[2 * mt + 1]) * w4.w;
    }
    acc += __shfl_xor(acc, 16); acc += __shfl_xor(acc, 32);
    if (q == 0 && (row0 + s) < p.nrows) p.out[row0 + s] = acc + P[PB_BOUT];
  }
}

extern "C" void kernel_launch(void* const* d_in, const int* in_sizes, int n_in,
                              void* d_out, int out_size, void* d_ws,
                              size_t ws_size, hipStream_t stream) {
  Params p;
  const float* const* in = (const float* const*)d_in;
  p.x        = in[0];  p.W_in     = in[1];  p.b_in     = in[2];
  p.g_in     = in[3];  p.be_in    = in[4];
  p.z_in_w   = in[5];  p.z_in_b   = in[6];
  p.z_out_w  = in[7];  p.z_out_b  = in[8];
  p.z_ffn_w1 = in[9];  p.z_ffn_b1 = in[10];
  p.z_ffn_w2 = in[11]; p.z_ffn_b2 = in[12];
  p.zn1_g    = in[13]; p.zn1_b    = in[14];
  p.zn2_g    = in[15]; p.zn2_b    = in[16];
  p.y_in_w   = in[17]; p.y_in_b   = in[18];
  p.y_out_w  = in[19]; p.y_out_b  = in[20];
  p.y_ffn_w1 = in[21]; p.y_ffn_b1 = in[22];
  p.y_ffn_w2 = in[23]; p.y_ffn_b2 = in[24];
  p.yn1_g    = in[25]; p.yn1_b    = in[26];
  p.yn2_g    = in[27]; p.yn2_b    = in[28];
  p.W_out    = in[29]; p.b_out    = in[30];
  p.out      = (float*)d_out;
  p.nrows    = in_sizes[0] / INDIM;

  if (ws_size < (size_t)NFRAG * 1024 + NPARAM * 4) return;
  ushort* wf = (ushort*)d_ws;

  hipLaunchKernelGGL(prepack_kernel, dim3(NFRAG + 1), dim3(64), 0, stream, p, wf);
  hipLaunchKernelGGL(trm_mfma_kernel, dim3(256), dim3(512), 0, stream, p, wf);
}

// Round 7
// 974.119 us; speedup vs baseline: 1.2136x; 1.0154x over previous
//
#include <hip/hip_runtime.h>
#include <math.h>

// ---------------------------------------------------------------------------
// Round 7: 4 waves/SIMD.
//   - R6 proved the kernel fits 128 VGPRs spill-free => 4 waves/EU is legal.
//   - Blocker was LDS: H (128-wide) TH buffer. Removed: gelu(h) packed in
//     regs and c2b'd into 4 B-frags; FFN2 consumes register B (layerBK<4,4>).
//   - TH now 64-wide only (2.3 KB/wave); arena 157.7 KB with 16 waves.
//   - 1024-thread blocks, flat_work_group_size(1024,1024)+waves_per_eu(4,4).
// ---------------------------------------------------------------------------

constexpr int STEPS = 16;
constexpr int INDIM = 200;

typedef __attribute__((ext_vector_type(8))) short bfrag8;   // 8 bf16 = 4 VGPR
typedef __attribute__((ext_vector_type(4))) float f32x4;
typedef __attribute__((ext_vector_type(4))) short s16x4;

constexpr int FB_WIN  = 0;    // W_in: mt(4) x kt(7)
constexpr int NFRAG   = 140;
constexpr int NPARAM  = 1544;

// LDS-resident steady frag indices (= global index - 28)
constexpr int LB_ZQ   = 0;
constexpr int LB_ZK   = 8;
constexpr int LB_ZV   = 16;
constexpr int LB_ZOUT = 24;
constexpr int LB_ZF1  = 32;
constexpr int LB_ZF2  = 48;
constexpr int LB_YV   = 64;
constexpr int LB_YOUT = 72;
constexpr int LB_YF1  = 80;
constexpr int LB_YF2  = 96;
constexpr int NSTEADY = 112;

// packed param float offsets
constexpr int PB_BIN   = 0;
constexpr int PB_GIN   = 64;
constexpr int PB_BEIN  = 128;
constexpr int PB_ZINB  = 192;
constexpr int PB_ZOUTB = 384;
constexpr int PB_ZF1B  = 448;
constexpr int PB_ZF2B  = 576;
constexpr int PB_ZN1G  = 640;
constexpr int PB_ZN1B  = 704;
constexpr int PB_ZN2G  = 768;
constexpr int PB_ZN2B  = 832;
constexpr int PB_YVB   = 896;
constexpr int PB_YOUTB = 960;
constexpr int PB_YF1B  = 1024;
constexpr int PB_YF2B  = 1152;
constexpr int PB_YN1G  = 1216;
constexpr int PB_YN1B  = 1280;
constexpr int PB_YN2G  = 1344;
constexpr int PB_YN2B  = 1408;
constexpr int PB_WOUT  = 1472;
constexpr int PB_BOUT  = 1536;

// LDS arena layout (shorts)
constexpr int S64      = 72;
constexpr int L_W      = 0;                       // 112 frags = 57,344 shorts
constexpr int L_P      = 57344;                   // 3,088 shorts
constexpr int L_ACT    = 60432;                   // 16 waves x TH(64-wide)
constexpr int WAVE_SH  = 1152;                    // 16 samples x 72 shorts
constexpr int NWAVE    = 16;
constexpr int ARENA_SH = L_ACT + NWAVE * WAVE_SH; // 78,864 shorts = 157,728 B

struct Params {
  const float *x, *W_in, *b_in, *g_in, *be_in;
  const float *z_in_w, *z_in_b, *z_out_w, *z_out_b;
  const float *z_ffn_w1, *z_ffn_b1, *z_ffn_w2, *z_ffn_b2;
  const float *zn1_g, *zn1_b, *zn2_g, *zn2_b;
  const float *y_in_w, *y_in_b, *y_out_w, *y_out_b;
  const float *y_ffn_w1, *y_ffn_b1, *y_ffn_w2, *y_ffn_b2;
  const float *yn1_g, *yn1_b, *yn2_g, *yn2_b;
  const float *W_out, *b_out;
  float *out;
  int nrows;
};

__device__ __forceinline__ ushort f2bf(float f) {
  uint u = __float_as_uint(f);
  u += 0x7FFFu + ((u >> 16) & 1u);
  return (ushort)(u >> 16);
}
__device__ __forceinline__ uint pk2(float a, float b) {
  return (uint)f2bf(a) | ((uint)f2bf(b) << 16);
}
__device__ __forceinline__ float upk_lo(uint u) {
  return __uint_as_float(u << 16);
}
__device__ __forceinline__ float upk_hi(uint u) {
  return __uint_as_float(u & 0xFFFF0000u);
}
__device__ __forceinline__ float dot4(f32x4 a, f32x4 b) {
  return a.x * b.x + a.y * b.y + a.z * b.z + a.w * b.w;
}
__device__ __forceinline__ void stc(short* buf, int stride, int mt, int q,
                                    int s, f32x4 c) {
  s16x4 v;
  v.x = (short)f2bf(c.x); v.y = (short)f2bf(c.y);
  v.z = (short)f2bf(c.z); v.w = (short)f2bf(c.w);
  *(s16x4*)(buf + s * stride + mt * 16 + q * 4) = v;
}

// C-layout (packed bf16 pairs p[8], tiles T..T+3) -> 2 MFMA B-frags
// covering the 64 feats those tiles span. Verified in R4.
__device__ __forceinline__ void c2b_p(const uint p[8], bfrag8& b0, bfrag8& b1,
                                      int lane) {
  const int srcA = (lane & 15) | ((lane & 16) << 1);  // s + 32*(q&1)
  const int srcB = srcA + 16;
  const bool odd = (lane & 32) != 0;                  // q>=2 wants mt 1,3
  uint ev0 = p[0], ev1 = p[1], ev2 = p[4], ev3 = p[5];
  uint od0 = p[2], od1 = p[3], od2 = p[6], od3 = p[7];
  uint rA0, rA1, rA2, rA3, rB0, rB1, rB2, rB3;
  {
    uint e, o;
    e = (uint)__shfl((int)ev0, srcA); o = (uint)__shfl((int)od0, srcA); rA0 = odd ? o : e;
    e = (uint)__shfl((int)ev1, srcA); o = (uint)__shfl((int)od1, srcA); rA1 = odd ? o : e;
    e = (uint)__shfl((int)ev2, srcA); o = (uint)__shfl((int)od2, srcA); rA2 = odd ? o : e;
    e = (uint)__shfl((int)ev3, srcA); o = (uint)__shfl((int)od3, srcA); rA3 = odd ? o : e;
    e = (uint)__shfl((int)ev0, srcB); o = (uint)__shfl((int)od0, srcB); rB0 = odd ? o : e;
    e = (uint)__shfl((int)ev1, srcB); o = (uint)__shfl((int)od1, srcB); rB1 = odd ? o : e;
    e = (uint)__shfl((int)ev2, srcB); o = (uint)__shfl((int)od2, srcB); rB2 = odd ? o : e;
    e = (uint)__shfl((int)ev3, srcB); o = (uint)__shfl((int)od3, srcB); rB3 = odd ? o : e;
  }
  union U { uint u[4]; bfrag8 b; };
  U u0, u1;
  u0.u[0] = rA0; u0.u[1] = rA1; u0.u[2] = rB0; u0.u[3] = rB1;
  u1.u[0] = rA2; u1.u[1] = rA3; u1.u[2] = rB2; u1.u[3] = rB3;
  b0 = u0.b; b1 = u1.b;
}
__device__ __forceinline__ void c2b(const f32x4 c[4], bfrag8& b0, bfrag8& b1,
                                    int lane) {
  uint p[8];
#pragma unroll
  for (int mt = 0; mt < 4; ++mt) {
    p[2 * mt]     = pk2(c[mt].x, c[mt].y);
    p[2 * mt + 1] = pk2(c[mt].z, c[mt].w);
  }
  c2b_p(p, b0, b1, lane);
}

// c[mt] = W * X^T + bias; B from LDS (TH scratch, 64-wide).
template <int MT>
__device__ __forceinline__ void layerN(const short* in, const short* lw,
                                       int fbase, const float* bias, f32x4* c,
                                       int lane, int q, int s) {
  bfrag8 bf[2];
#pragma unroll
  for (int kt = 0; kt < 2; ++kt)
    bf[kt] = *(const bfrag8*)(in + s * S64 + kt * 32 + q * 8);
#pragma unroll
  for (int mt = 0; mt < MT; ++mt)
    c[mt] = *(const f32x4*)(bias + mt * 16 + q * 4);
#pragma unroll
  for (int mt = 0; mt < MT; ++mt) {
#pragma unroll
    for (int kt = 0; kt < 2; ++kt) {
      bfrag8 af = *(const bfrag8*)(lw + (fbase + mt * 2 + kt) * 512 + lane * 8);
      c[mt] = __builtin_amdgcn_mfma_f32_16x16x32_bf16(af, bf[kt], c[mt], 0, 0, 0);
    }
  }
}

// B from registers, KT k-tiles.
template <int MT, int KT>
__device__ __forceinline__ void layerBK(const bfrag8* bf, const short* lw,
                                        int fbase, const float* bias, f32x4* c,
                                        int lane, int q) {
#pragma unroll
  for (int mt = 0; mt < MT; ++mt)
    c[mt] = *(const f32x4*)(bias + mt * 16 + q * 4);
#pragma unroll
  for (int mt = 0; mt < MT; ++mt) {
#pragma unroll
    for (int kt = 0; kt < KT; ++kt) {
      bfrag8 af = *(const bfrag8*)(lw + (fbase + mt * KT + kt) * 512 + lane * 8);
      c[mt] = __builtin_amdgcn_mfma_f32_16x16x32_bf16(af, bf[kt], c[mt], 0, 0, 0);
    }
  }
}

// Two B inputs through the same weights: A-frag read once.
template <int MT>
__device__ __forceinline__ void layerB2(const bfrag8* bfA, const bfrag8* bfB,
                                        const short* lw, int fbase,
                                        const float* bias, f32x4* cA, f32x4* cB,
                                        int lane, int q) {
#pragma unroll
  for (int mt = 0; mt < MT; ++mt) {
    f32x4 b4 = *(const f32x4*)(bias + mt * 16 + q * 4);
    cA[mt] = b4; cB[mt] = b4;
  }
#pragma unroll
  for (int mt = 0; mt < MT; ++mt) {
#pragma unroll
    for (int kt = 0; kt < 2; ++kt) {
      bfrag8 af = *(const bfrag8*)(lw + (fbase + mt * 2 + kt) * 512 + lane * 8);
      cA[mt] = __builtin_amdgcn_mfma_f32_16x16x32_bf16(af, bfA[kt], cA[mt], 0, 0, 0);
      cB[mt] = __builtin_amdgcn_mfma_f32_16x16x32_bf16(af, bfB[kt], cB[mt], 0, 0, 0);
    }
  }
}

__device__ __forceinline__ void lnorm_c(f32x4 c[4], const float* g,
                                        const float* b, int q) {
  float sm = 0.f;
#pragma unroll
  for (int mt = 0; mt < 4; ++mt) sm += c[mt].x + c[mt].y + c[mt].z + c[mt].w;
  sm += __shfl_xor(sm, 16); sm += __shfl_xor(sm, 32);
  float mean = sm * (1.f / 64.f);
  float vs = 0.f;
#pragma unroll
  for (int mt = 0; mt < 4; ++mt) {
    f32x4 d = c[mt];
    d.x -= mean; d.y -= mean; d.z -= mean; d.w -= mean;
    c[mt] = d;
    vs += d.x * d.x + d.y * d.y + d.z * d.z + d.w * d.w;
  }
  vs += __shfl_xor(vs, 16); vs += __shfl_xor(vs, 32);
  float rs = rsqrtf(vs * (1.f / 64.f) + 1e-5f);
#pragma unroll
  for (int mt = 0; mt < 4; ++mt) {
    f32x4 g4 = *(const f32x4*)(g + mt * 16 + q * 4);
    f32x4 b4 = *(const f32x4*)(b + mt * 16 + q * 4);
    f32x4 v = c[mt];
    v.x = v.x * rs * g4.x + b4.x; v.y = v.y * rs * g4.y + b4.y;
    v.z = v.z * rs * g4.z + b4.z; v.w = v.w * rs * g4.w + b4.w;
    c[mt] = v;
  }
}

__device__ __forceinline__ float gelu1(float x) {
  float ax = fabsf(x) * 0.70710678118654752f;
  float t = __builtin_amdgcn_rcpf(1.0f + 0.3275911f * ax);
  float poly =
      ((((1.061405429f * t - 1.453152027f) * t + 1.421413741f) * t -
        0.284496736f) * t + 0.254829592f) * t;
  float e = __expf(-ax * ax);
  float erfv = copysignf(1.0f - poly * e, x);
  return 0.5f * x * (1.0f + erfv);
}

// ---------------------------------------------------------------------------
// prepack: weights -> A-frag bf16 order; params -> packed fp32 array
// ---------------------------------------------------------------------------
__global__ void prepack_kernel(Params p, ushort* wf) {
  int f = blockIdx.x;
  int lane = threadIdx.x;

  if (f == NFRAG) {
    float* pw = (float*)(wf + (size_t)NFRAG * 512);
    for (int t = lane; t < NPARAM; t += 64) {
      float v = 0.f;
      if      (t < 64)   v = p.b_in[t];
      else if (t < 128)  v = p.g_in[t - 64];
      else if (t < 192)  v = p.be_in[t - 128];
      else if (t < 384)  v = p.z_in_b[t - 192];
      else if (t < 448)  v = p.z_out_b[t - 384];
      else if (t < 576)  v = p.z_ffn_b1[t - 448];
      else if (t < 640)  v = p.z_ffn_b2[t - 576];
      else if (t < 704)  v = p.zn1_g[t - 640];
      else if (t < 768)  v = p.zn1_b[t - 704];
      else if (t < 832)  v = p.zn2_g[t - 768];
      else if (t < 896)  v = p.zn2_b[t - 832];
      else if (t < 960)  v = p.y_in_b[128 + t - 896];
      else if (t < 1024) v = p.y_out_b[t - 960];
      else if (t < 1152) v = p.y_ffn_b1[t - 1024];
      else if (t < 1216) v = p.y_ffn_b2[t - 1152];
      else if (t < 1280) v = p.yn1_g[t - 1216];
      else if (t < 1344) v = p.yn1_b[t - 1280];
      else if (t < 1408) v = p.yn2_g[t - 1344];
      else if (t < 1472) v = p.yn2_b[t - 1408];
      else if (t < 1536) v = p.W_out[t - 1472];
      else if (t == 1536) v = p.b_out[0];
      pw[t] = v;
    }
    return;
  }

  int q = lane >> 4, r = lane & 15;
  const float* src; int K, mt, kt, l;
  if (f < 28)        { src = p.W_in;                K = 200; mt = f / 7;  kt = f % 7; }
  else if (f < 36)   { l = f - 28;  src = p.z_in_w;            K = 64;  mt = l / 2; kt = l % 2; }
  else if (f < 44)   { l = f - 36;  src = p.z_in_w + 64 * 64;  K = 64;  mt = l / 2; kt = l % 2; }
  else if (f < 52)   { l = f - 44;  src = p.z_in_w + 128 * 64; K = 64;  mt = l / 2; kt = l % 2; }
  else if (f < 60)   { l = f - 52;  src = p.z_out_w;           K = 64;  mt = l / 2; kt = l % 2; }
  else if (f < 76)   { l = f - 60;  src = p.z_ffn_w1;          K = 64;  mt = l / 2; kt = l % 2; }
  else if (f < 92)   { l = f - 76;  src = p.z_ffn_w2;          K = 128; mt = l / 4; kt = l % 4; }
  else if (f < 100)  { l = f - 92;  src = p.y_in_w + 128 * 64; K = 64;  mt = l / 2; kt = l % 2; }
  else if (f < 108)  { l = f - 100; src = p.y_out_w;           K = 64;  mt = l / 2; kt = l % 2; }
  else if (f < 124)  { l = f - 108; src = p.y_ffn_w1;          K = 64;  mt = l / 2; kt = l % 2; }
  else               { l = f - 124; src = p.y_ffn_w2;          K = 128; mt = l / 4; kt = l % 4; }

  int row = mt * 16 + r;
  int col = kt * 32 + q * 8;
  bfrag8 o;
#pragma unroll
  for (int j = 0; j < 8; ++j) {
    int cc = col + j;
    float v = (cc < K) ? src[(size_t)row * K + cc] : 0.0f;
    o[j] = (short)f2bf(v);
  }
  *(bfrag8*)(wf + (size_t)f * 512 + lane * 8) = o;
}

// ---------------------------------------------------------------------------
// main kernel: 1024 thr (16 waves) x 256 blocks; 4 waves/SIMD; weights in LDS.
// ---------------------------------------------------------------------------
__global__
__attribute__((amdgpu_flat_work_group_size(1024, 1024), amdgpu_waves_per_eu(4, 4)))
void trm_mfma_kernel(Params p, const ushort* wf) {
  __shared__ __align__(16) short arena[ARENA_SH];
  const int tid = threadIdx.x;
  const int wave = tid >> 6, lane = tid & 63;
  const int q = lane >> 4, s = lane & 15;

  // ---- stage steady weights + params into LDS (once per block) ----
  {
    const uint4* srcw = (const uint4*)(wf + (size_t)28 * 512);
    uint4* dstw = (uint4*)(arena + L_W);
    for (int i = tid; i < NSTEADY * 64; i += 1024) dstw[i] = srcw[i];
    const uint4* srcp = (const uint4*)(wf + (size_t)NFRAG * 512);
    uint4* dstp = (uint4*)(arena + L_P);
    for (int i = tid; i < NPARAM / 4; i += 1024) dstp[i] = srcp[i];
  }
  __syncthreads();  // the only barrier

  const short* LW = arena + L_W;
  const float* P  = (const float*)(arena + L_P);
  short* TH = arena + L_ACT + wave * WAVE_SH;

  const int chunks = (p.nrows + 255) / 256;
  for (int ic = blockIdx.x; ic < chunks; ic += gridDim.x) {
    const int row0 = ic * 256 + wave * 16;
    int row = row0 + s;
    if (row >= p.nrows) row = p.nrows - 1;

    // ---- x_proj = gelu(ln(x @ W_in^T + b_in)); stays in registers ----
    bfrag8 xpB[2];
    {
      const float* xr = p.x + (size_t)row * INDIM;
      bfrag8 xb[7];
#pragma unroll
      for (int kt = 0; kt < 7; ++kt) {
        int k0i = kt * 32 + q * 8;
        bfrag8 t;
        if (kt < 6 || q == 0) {
          f32x4 lo = *(const f32x4*)(xr + k0i);
          f32x4 hi = *(const f32x4*)(xr + k0i + 4);
          t[0] = (short)f2bf(lo.x); t[1] = (short)f2bf(lo.y);
          t[2] = (short)f2bf(lo.z); t[3] = (short)f2bf(lo.w);
          t[4] = (short)f2bf(hi.x); t[5] = (short)f2bf(hi.y);
          t[6] = (short)f2bf(hi.z); t[7] = (short)f2bf(hi.w);
        } else {
#pragma unroll
          for (int j = 0; j < 8; ++j) t[j] = 0;
        }
        xb[kt] = t;
      }
      f32x4 c[4];
#pragma unroll
      for (int mt = 0; mt < 4; ++mt)
        c[mt] = *(const f32x4*)(P + PB_BIN + mt * 16 + q * 4);
#pragma unroll
      for (int mt = 0; mt < 4; ++mt)
#pragma unroll
        for (int kt = 0; kt < 7; ++kt) {
          bfrag8 af =
              *(const bfrag8*)(wf + (size_t)(FB_WIN + mt * 7 + kt) * 512 + lane * 8);
          c[mt] = __builtin_amdgcn_mfma_f32_16x16x32_bf16(af, xb[kt], c[mt], 0, 0, 0);
        }
      lnorm_c(c, P + PB_GIN, P + PB_BEIN, q);
#pragma unroll
      for (int mt = 0; mt < 4; ++mt) {
        c[mt].x = gelu1(c[mt].x); c[mt].y = gelu1(c[mt].y);
        c[mt].z = gelu1(c[mt].z); c[mt].w = gelu1(c[mt].w);
      }
      c2b(c, xpB[0], xpB[1], lane);
    }

    // ---- k0/v0 packed bf16 in registers; zero state ----
    uint k0p[8], v0p[8], zCp[8], yCp[8];
    bfrag8 zB[2], yB[2];
    {
      f32x4 ck[4], cv[4];
      layerBK<4, 2>(xpB, LW, LB_ZK, P + PB_ZINB + 64, ck, lane, q);
      layerBK<4, 2>(xpB, LW, LB_ZV, P + PB_ZINB + 128, cv, lane, q);
#pragma unroll
      for (int mt = 0; mt < 4; ++mt) {
        k0p[2 * mt]     = pk2(ck[mt].x, ck[mt].y);
        k0p[2 * mt + 1] = pk2(ck[mt].z, ck[mt].w);
        v0p[2 * mt]     = pk2(cv[mt].x, cv[mt].y);
        v0p[2 * mt + 1] = pk2(cv[mt].z, cv[mt].w);
        zCp[2 * mt] = 0u; zCp[2 * mt + 1] = 0u;
        yCp[2 * mt] = 0u; yCp[2 * mt + 1] = 0u;
      }
#pragma unroll
      for (int kt = 0; kt < 2; ++kt) {
        bfrag8 t;
#pragma unroll
        for (int j = 0; j < 8; ++j) t[j] = 0;
        zB[kt] = t; yB[kt] = t;
      }
    }

    // ---- 16 recursive steps ----
    for (int st = 0; st < STEPS; ++st) {
      // -- attention k-phase: scores + softmax, k regs freed after --
      float w0[4], w1[4], w2[4], wi[4];
      {
        f32x4 q2[4], kz[4], ky[4];
        layerBK<4, 2>(zB, LW, LB_ZQ, P + PB_ZINB, q2, lane, q);
        layerB2<4>(zB, yB, LW, LB_ZK, P + PB_ZINB + 64, kz, ky, lane, q);
#pragma unroll
        for (int mt = 0; mt < 4; ++mt) {
          float a0 = q2[mt].x * upk_lo(k0p[2 * mt]) +
                     q2[mt].y * upk_hi(k0p[2 * mt]) +
                     q2[mt].z * upk_lo(k0p[2 * mt + 1]) +
                     q2[mt].w * upk_hi(k0p[2 * mt + 1]);
          float a1 = dot4(q2[mt], ky[mt]);
          float a2 = dot4(q2[mt], kz[mt]);
          a0 += __shfl_xor(a0, 16); a0 += __shfl_xor(a0, 32);
          a1 += __shfl_xor(a1, 16); a1 += __shfl_xor(a1, 32);
          a2 += __shfl_xor(a2, 16); a2 += __shfl_xor(a2, 32);
          a0 *= 0.25f; a1 *= 0.25f; a2 *= 0.25f;
          float mx = fmaxf(a0, fmaxf(a1, a2));
          float e0 = __expf(a0 - mx), e1 = __expf(a1 - mx), e2 = __expf(a2 - mx);
          w0[mt] = e0; w1[mt] = e1; w2[mt] = e2;
          wi[mt] = __builtin_amdgcn_rcpf(e0 + e1 + e2);
        }
      }
      // -- attention v-phase --
      {
        f32x4 vz[4], vy[4];
        layerB2<4>(zB, yB, LW, LB_ZV, P + PB_ZINB + 128, vz, vy, lane, q);
#pragma unroll
        for (int mt = 0; mt < 4; ++mt) {
          f32x4 o;
          o.x = (upk_lo(v0p[2 * mt])     * w0[mt] + vy[mt].x * w1[mt] +
                 vz[mt].x * w2[mt]) * wi[mt];
          o.y = (upk_hi(v0p[2 * mt])     * w0[mt] + vy[mt].y * w1[mt] +
                 vz[mt].y * w2[mt]) * wi[mt];
          o.z = (upk_lo(v0p[2 * mt + 1]) * w0[mt] + vy[mt].z * w1[mt] +
                 vz[mt].z * w2[mt]) * wi[mt];
          o.w = (upk_hi(v0p[2 * mt + 1]) * w0[mt] + vy[mt].w * w1[mt] +
                 vz[mt].w * w2[mt]) * wi[mt];
          stc(TH, S64, mt, q, s, o);
        }
      }

      // -- z branch --
      uint zrp[8];
      {
        f32x4 zr[4];
        layerN<4>(TH, LW, LB_ZOUT, P + PB_ZOUTB, zr, lane, q, s);
#pragma unroll
        for (int mt = 0; mt < 4; ++mt) {
          zr[mt].x += upk_lo(zCp[2 * mt]);     zr[mt].y += upk_hi(zCp[2 * mt]);
          zr[mt].z += upk_lo(zCp[2 * mt + 1]); zr[mt].w += upk_hi(zCp[2 * mt + 1]);
        }
        lnorm_c(zr, P + PB_ZN1G, P + PB_ZN1B, q);
#pragma unroll
        for (int mt = 0; mt < 4; ++mt) {
          stc(TH, S64, mt, q, s, zr[mt]);
          zrp[2 * mt]     = pk2(zr[mt].x, zr[mt].y);
          zrp[2 * mt + 1] = pk2(zr[mt].z, zr[mt].w);
        }
      }

      // z-FFN: h = gelu(W1*zr+b1) entirely in regs -> 4 B-frags via c2b
      bfrag8 hB[4];
      {
        f32x4 h8[8];
        layerN<8>(TH, LW, LB_ZF1, P + PB_ZF1B, h8, lane, q, s);
#pragma unroll
        for (int g = 0; g < 2; ++g) {
          uint ph[8];
#pragma unroll
          for (int mt = 0; mt < 4; ++mt) {
            f32x4 h = h8[4 * g + mt];
            h.x = gelu1(h.x); h.y = gelu1(h.y);
            h.z = gelu1(h.z); h.w = gelu1(h.w);
            ph[2 * mt]     = pk2(h.x, h.y);
            ph[2 * mt + 1] = pk2(h.z, h.w);
          }
          c2b_p(ph, hB[2 * g], hB[2 * g + 1], lane);
        }
      }
      f32x4 z2[4];
      layerBK<4, 4>(hB, LW, LB_ZF2, P + PB_ZF2B, z2, lane, q);
#pragma unroll
      for (int mt = 0; mt < 4; ++mt) {
        z2[mt].x += upk_lo(zrp[2 * mt]);     z2[mt].y += upk_hi(zrp[2 * mt]);
        z2[mt].z += upk_lo(zrp[2 * mt + 1]); z2[mt].w += upk_hi(zrp[2 * mt + 1]);
      }
      lnorm_c(z2, P + PB_ZN2G, P + PB_ZN2B, q);
      {
        uint zp[8];
#pragma unroll
        for (int mt = 0; mt < 4; ++mt) {
          zp[2 * mt]     = pk2(z2[mt].x, z2[mt].y);
          zp[2 * mt + 1] = pk2(z2[mt].z, z2[mt].w);
          zCp[2 * mt] = zp[2 * mt]; zCp[2 * mt + 1] = zp[2 * mt + 1];
        }
        c2b_p(zp, zB[0], zB[1], lane);
      }

      // -- y branch --
      f32x4 t4[4];
      layerBK<4, 2>(zB, LW, LB_YV, P + PB_YVB, t4, lane, q);
#pragma unroll
      for (int mt = 0; mt < 4; ++mt) stc(TH, S64, mt, q, s, t4[mt]);

      uint yrp[8];
      {
        f32x4 yr[4];
        layerN<4>(TH, LW, LB_YOUT, P + PB_YOUTB, yr, lane, q, s);
#pragma unroll
        for (int mt = 0; mt < 4; ++mt) {
          yr[mt].x += upk_lo(yCp[2 * mt]);     yr[mt].y += upk_hi(yCp[2 * mt]);
          yr[mt].z += upk_lo(yCp[2 * mt + 1]); yr[mt].w += upk_hi(yCp[2 * mt + 1]);
        }
        lnorm_c(yr, P + PB_YN1G, P + PB_YN1B, q);
#pragma unroll
        for (int mt = 0; mt < 4; ++mt) {
          stc(TH, S64, mt, q, s, yr[mt]);
          yrp[2 * mt]     = pk2(yr[mt].x, yr[mt].y);
          yrp[2 * mt + 1] = pk2(yr[mt].z, yr[mt].w);
        }
      }

      // y-FFN: same register-resident h path
      {
        f32x4 h8[8];
        layerN<8>(TH, LW, LB_YF1, P + PB_YF1B, h8, lane, q, s);
#pragma unroll
        for (int g = 0; g < 2; ++g) {
          uint ph[8];
#pragma unroll
          for (int mt = 0; mt < 4; ++mt) {
            f32x4 h = h8[4 * g + mt];
            h.x = gelu1(h.x); h.y = gelu1(h.y);
            h.z = gelu1(h.z); h.w = gelu1(h.w);
            ph[2 * mt]     = pk2(h.x, h.y);
            ph[2 * mt + 1] = pk2(h.z, h.w);
          }
          c2b_p(ph, hB[2 * g], hB[2 * g + 1], lane);
        }
      }
      f32x4 y2[4];
      layerBK<4, 4>(hB, LW, LB_YF2, P + PB_YF2B, y2, lane, q);
#pragma unroll
      for (int mt = 0; mt < 4; ++mt) {
        y2[mt].x += upk_lo(yrp[2 * mt]);     y2[mt].y += upk_hi(yrp[2 * mt]);
        y2[mt].z += upk_lo(yrp[2 * mt + 1]); y2[mt].w += upk_hi(yrp[2 * mt + 1]);
      }
      lnorm_c(y2, P + PB_YN2G, P + PB_YN2B, q);
      {
        uint yp[8];
#pragma unroll
        for (int mt = 0; mt < 4; ++mt) {
          yp[2 * mt]     = pk2(y2[mt].x, y2[mt].y);
          yp[2 * mt + 1] = pk2(y2[mt].z, y2[mt].w);
          yCp[2 * mt] = yp[2 * mt]; yCp[2 * mt + 1] = yp[2 * mt + 1];
        }
        c2b_p(yp, yB[0], yB[1], lane);
      }
    }

    // ---- out = (y @ W_out^T + b_out)[:, 0] from packed carry ----
    float acc = 0.f;
#pragma unroll
    for (int mt = 0; mt < 4; ++mt) {
      f32x4 w4 = *(const f32x4*)(P + PB_WOUT + mt * 16 + q * 4);
      acc += upk_lo(yCp[2 * mt]) * w4.x + upk_hi(yCp[2 * mt]) * w4.y +
             upk_lo(yCp[2 * mt + 1]) * w4.z + upk_hi(yCp[2 * mt + 1]) * w4.w;
    }
    acc += __shfl_xor(acc, 16); acc += __shfl_xor(acc, 32);
    if (q == 0 && (row0 + s) < p.nrows) p.out[row0 + s] = acc + P[PB_BOUT];
  }
}

extern "C" void kernel_launch(void* const* d_in, const int* in_sizes, int n_in,
                              void* d_out, int out_size, void* d_ws,
                              size_t ws_size, hipStream_t stream) {
  Params p;
  const float* const* in = (const float* const*)d_in;
  p.x        = in[0];  p.W_in     = in[1];  p.b_in     = in[2];
  p.g_in     = in[3];  p.be_in    = in[4];
  p.z_in_w   = in[5];  p.z_in_b   = in[6];
  p.z_out_w  = in[7];  p.z_out_b  = in[8];
  p.z_ffn_w1 = in[9];  p.z_ffn_b1 = in[10];
  p.z_ffn_w2 = in[11]; p.z_ffn_b2 = in[12];
  p.zn1_g    = in[13]; p.zn1_b    = in[14];
  p.zn2_g    = in[15]; p.zn2_b    = in[16];
  p.y_in_w   = in[17]; p.y_in_b   = in[18];
  p.y_out_w  = in[19]; p.y_out_b  = in[20];
  p.y_ffn_w1 = in[21]; p.y_ffn_b1 = in[22];
  p.y_ffn_w2 = in[23]; p.y_ffn_b2 = in[24];
  p.yn1_g    = in[25]; p.yn1_b    = in[26];
  p.yn2_g    = in[27]; p.yn2_b    = in[28];
  p.W_out    = in[29]; p.b_out    = in[30];
  p.out      = (float*)d_out;
  p.nrows    = in_sizes[0] / INDIM;

  if (ws_size < (size_t)NFRAG * 1024 + NPARAM * 4) return;
  ushort* wf = (ushort*)d_ws;

  hipLaunchKernelGGL(prepack_kernel, dim3(NFRAG + 1), dim3(64), 0, stream, p, wf);
  hipLaunchKernelGGL(trm_mfma_kernel, dim3(256), dim3(1024), 0, stream, p, wf);
}

// Round 8
// 957.072 us; speedup vs baseline: 1.2352x; 1.0178x over previous
//
#include <hip/hip_runtime.h>
#include <math.h>

// ---------------------------------------------------------------------------
// Round 8: R7 structure + correct VGPR control.
//   Allocator evidence: launch_bounds(256,1)->212, (512,2)->128,
//   waves_per_eu(2|2,2)->128, waves_per_eu(4,4)->64(!). Only launch_bounds
//   (min-blocks semantics) reliably sets the cap. (1024,1): 1 block/CU x 16
//   waves = 4 waves/EU -> 128-VGPR cap, which R6 proved spill-free.
// ---------------------------------------------------------------------------

constexpr int STEPS = 16;
constexpr int INDIM = 200;

typedef __attribute__((ext_vector_type(8))) short bfrag8;   // 8 bf16 = 4 VGPR
typedef __attribute__((ext_vector_type(4))) float f32x4;
typedef __attribute__((ext_vector_type(4))) short s16x4;

constexpr int FB_WIN  = 0;    // W_in: mt(4) x kt(7)
constexpr int NFRAG   = 140;
constexpr int NPARAM  = 1544;

// LDS-resident steady frag indices (= global index - 28)
constexpr int LB_ZQ   = 0;
constexpr int LB_ZK   = 8;
constexpr int LB_ZV   = 16;
constexpr int LB_ZOUT = 24;
constexpr int LB_ZF1  = 32;
constexpr int LB_ZF2  = 48;
constexpr int LB_YV   = 64;
constexpr int LB_YOUT = 72;
constexpr int LB_YF1  = 80;
constexpr int LB_YF2  = 96;
constexpr int NSTEADY = 112;

// packed param float offsets
constexpr int PB_BIN   = 0;
constexpr int PB_GIN   = 64;
constexpr int PB_BEIN  = 128;
constexpr int PB_ZINB  = 192;
constexpr int PB_ZOUTB = 384;
constexpr int PB_ZF1B  = 448;
constexpr int PB_ZF2B  = 576;
constexpr int PB_ZN1G  = 640;
constexpr int PB_ZN1B  = 704;
constexpr int PB_ZN2G  = 768;
constexpr int PB_ZN2B  = 832;
constexpr int PB_YVB   = 896;
constexpr int PB_YOUTB = 960;
constexpr int PB_YF1B  = 1024;
constexpr int PB_YF2B  = 1152;
constexpr int PB_YN1G  = 1216;
constexpr int PB_YN1B  = 1280;
constexpr int PB_YN2G  = 1344;
constexpr int PB_YN2B  = 1408;
constexpr int PB_WOUT  = 1472;
constexpr int PB_BOUT  = 1536;

// LDS arena layout (shorts)
constexpr int S64      = 72;
constexpr int L_W      = 0;                       // 112 frags = 57,344 shorts
constexpr int L_P      = 57344;                   // 3,088 shorts
constexpr int L_ACT    = 60432;                   // 16 waves x TH(64-wide)
constexpr int WAVE_SH  = 1152;                    // 16 samples x 72 shorts
constexpr int NWAVE    = 16;
constexpr int ARENA_SH = L_ACT + NWAVE * WAVE_SH; // 78,864 shorts = 157,728 B

struct Params {
  const float *x, *W_in, *b_in, *g_in, *be_in;
  const float *z_in_w, *z_in_b, *z_out_w, *z_out_b;
  const float *z_ffn_w1, *z_ffn_b1, *z_ffn_w2, *z_ffn_b2;
  const float *zn1_g, *zn1_b, *zn2_g, *zn2_b;
  const float *y_in_w, *y_in_b, *y_out_w, *y_out_b;
  const float *y_ffn_w1, *y_ffn_b1, *y_ffn_w2, *y_ffn_b2;
  const float *yn1_g, *yn1_b, *yn2_g, *yn2_b;
  const float *W_out, *b_out;
  float *out;
  int nrows;
};

__device__ __forceinline__ ushort f2bf(float f) {
  uint u = __float_as_uint(f);
  u += 0x7FFFu + ((u >> 16) & 1u);
  return (ushort)(u >> 16);
}
__device__ __forceinline__ uint pk2(float a, float b) {
  return (uint)f2bf(a) | ((uint)f2bf(b) << 16);
}
__device__ __forceinline__ float upk_lo(uint u) {
  return __uint_as_float(u << 16);
}
__device__ __forceinline__ float upk_hi(uint u) {
  return __uint_as_float(u & 0xFFFF0000u);
}
__device__ __forceinline__ float dot4(f32x4 a, f32x4 b) {
  return a.x * b.x + a.y * b.y + a.z * b.z + a.w * b.w;
}
__device__ __forceinline__ void stc(short* buf, int stride, int mt, int q,
                                    int s, f32x4 c) {
  s16x4 v;
  v.x = (short)f2bf(c.x); v.y = (short)f2bf(c.y);
  v.z = (short)f2bf(c.z); v.w = (short)f2bf(c.w);
  *(s16x4*)(buf + s * stride + mt * 16 + q * 4) = v;
}

// C-layout (packed bf16 pairs p[8]) -> 2 MFMA B-frags. Verified in R4.
__device__ __forceinline__ void c2b_p(const uint p[8], bfrag8& b0, bfrag8& b1,
                                      int lane) {
  const int srcA = (lane & 15) | ((lane & 16) << 1);  // s + 32*(q&1)
  const int srcB = srcA + 16;
  const bool odd = (lane & 32) != 0;                  // q>=2 wants mt 1,3
  uint ev0 = p[0], ev1 = p[1], ev2 = p[4], ev3 = p[5];
  uint od0 = p[2], od1 = p[3], od2 = p[6], od3 = p[7];
  uint rA0, rA1, rA2, rA3, rB0, rB1, rB2, rB3;
  {
    uint e, o;
    e = (uint)__shfl((int)ev0, srcA); o = (uint)__shfl((int)od0, srcA); rA0 = odd ? o : e;
    e = (uint)__shfl((int)ev1, srcA); o = (uint)__shfl((int)od1, srcA); rA1 = odd ? o : e;
    e = (uint)__shfl((int)ev2, srcA); o = (uint)__shfl((int)od2, srcA); rA2 = odd ? o : e;
    e = (uint)__shfl((int)ev3, srcA); o = (uint)__shfl((int)od3, srcA); rA3 = odd ? o : e;
    e = (uint)__shfl((int)ev0, srcB); o = (uint)__shfl((int)od0, srcB); rB0 = odd ? o : e;
    e = (uint)__shfl((int)ev1, srcB); o = (uint)__shfl((int)od1, srcB); rB1 = odd ? o : e;
    e = (uint)__shfl((int)ev2, srcB); o = (uint)__shfl((int)od2, srcB); rB2 = odd ? o : e;
    e = (uint)__shfl((int)ev3, srcB); o = (uint)__shfl((int)od3, srcB); rB3 = odd ? o : e;
  }
  union U { uint u[4]; bfrag8 b; };
  U u0, u1;
  u0.u[0] = rA0; u0.u[1] = rA1; u0.u[2] = rB0; u0.u[3] = rB1;
  u1.u[0] = rA2; u1.u[1] = rA3; u1.u[2] = rB2; u1.u[3] = rB3;
  b0 = u0.b; b1 = u1.b;
}
__device__ __forceinline__ void c2b(const f32x4 c[4], bfrag8& b0, bfrag8& b1,
                                    int lane) {
  uint p[8];
#pragma unroll
  for (int mt = 0; mt < 4; ++mt) {
    p[2 * mt]     = pk2(c[mt].x, c[mt].y);
    p[2 * mt + 1] = pk2(c[mt].z, c[mt].w);
  }
  c2b_p(p, b0, b1, lane);
}

// c[mt] = W * X^T + bias; B from LDS (TH scratch, 64-wide).
template <int MT>
__device__ __forceinline__ void layerN(const short* in, const short* lw,
                                       int fbase, const float* bias, f32x4* c,
                                       int lane, int q, int s) {
  bfrag8 bf[2];
#pragma unroll
  for (int kt = 0; kt < 2; ++kt)
    bf[kt] = *(const bfrag8*)(in + s * S64 + kt * 32 + q * 8);
#pragma unroll
  for (int mt = 0; mt < MT; ++mt)
    c[mt] = *(const f32x4*)(bias + mt * 16 + q * 4);
#pragma unroll
  for (int mt = 0; mt < MT; ++mt) {
#pragma unroll
    for (int kt = 0; kt < 2; ++kt) {
      bfrag8 af = *(const bfrag8*)(lw + (fbase + mt * 2 + kt) * 512 + lane * 8);
      c[mt] = __builtin_amdgcn_mfma_f32_16x16x32_bf16(af, bf[kt], c[mt], 0, 0, 0);
    }
  }
}

// B from registers, KT k-tiles.
template <int MT, int KT>
__device__ __forceinline__ void layerBK(const bfrag8* bf, const short* lw,
                                        int fbase, const float* bias, f32x4* c,
                                        int lane, int q) {
#pragma unroll
  for (int mt = 0; mt < MT; ++mt)
    c[mt] = *(const f32x4*)(bias + mt * 16 + q * 4);
#pragma unroll
  for (int mt = 0; mt < MT; ++mt) {
#pragma unroll
    for (int kt = 0; kt < KT; ++kt) {
      bfrag8 af = *(const bfrag8*)(lw + (fbase + mt * KT + kt) * 512 + lane * 8);
      c[mt] = __builtin_amdgcn_mfma_f32_16x16x32_bf16(af, bf[kt], c[mt], 0, 0, 0);
    }
  }
}

// Two B inputs through the same weights: A-frag read once.
template <int MT>
__device__ __forceinline__ void layerB2(const bfrag8* bfA, const bfrag8* bfB,
                                        const short* lw, int fbase,
                                        const float* bias, f32x4* cA, f32x4* cB,
                                        int lane, int q) {
#pragma unroll
  for (int mt = 0; mt < MT; ++mt) {
    f32x4 b4 = *(const f32x4*)(bias + mt * 16 + q * 4);
    cA[mt] = b4; cB[mt] = b4;
  }
#pragma unroll
  for (int mt = 0; mt < MT; ++mt) {
#pragma unroll
    for (int kt = 0; kt < 2; ++kt) {
      bfrag8 af = *(const bfrag8*)(lw + (fbase + mt * 2 + kt) * 512 + lane * 8);
      cA[mt] = __builtin_amdgcn_mfma_f32_16x16x32_bf16(af, bfA[kt], cA[mt], 0, 0, 0);
      cB[mt] = __builtin_amdgcn_mfma_f32_16x16x32_bf16(af, bfB[kt], cB[mt], 0, 0, 0);
    }
  }
}

__device__ __forceinline__ void lnorm_c(f32x4 c[4], const float* g,
                                        const float* b, int q) {
  float sm = 0.f;
#pragma unroll
  for (int mt = 0; mt < 4; ++mt) sm += c[mt].x + c[mt].y + c[mt].z + c[mt].w;
  sm += __shfl_xor(sm, 16); sm += __shfl_xor(sm, 32);
  float mean = sm * (1.f / 64.f);
  float vs = 0.f;
#pragma unroll
  for (int mt = 0; mt < 4; ++mt) {
    f32x4 d = c[mt];
    d.x -= mean; d.y -= mean; d.z -= mean; d.w -= mean;
    c[mt] = d;
    vs += d.x * d.x + d.y * d.y + d.z * d.z + d.w * d.w;
  }
  vs += __shfl_xor(vs, 16); vs += __shfl_xor(vs, 32);
  float rs = rsqrtf(vs * (1.f / 64.f) + 1e-5f);
#pragma unroll
  for (int mt = 0; mt < 4; ++mt) {
    f32x4 g4 = *(const f32x4*)(g + mt * 16 + q * 4);
    f32x4 b4 = *(const f32x4*)(b + mt * 16 + q * 4);
    f32x4 v = c[mt];
    v.x = v.x * rs * g4.x + b4.x; v.y = v.y * rs * g4.y + b4.y;
    v.z = v.z * rs * g4.z + b4.z; v.w = v.w * rs * g4.w + b4.w;
    c[mt] = v;
  }
}

__device__ __forceinline__ float gelu1(float x) {
  float ax = fabsf(x) * 0.70710678118654752f;
  float t = __builtin_amdgcn_rcpf(1.0f + 0.3275911f * ax);
  float poly =
      ((((1.061405429f * t - 1.453152027f) * t + 1.421413741f) * t -
        0.284496736f) * t + 0.254829592f) * t;
  float e = __expf(-ax * ax);
  float erfv = copysignf(1.0f - poly * e, x);
  return 0.5f * x * (1.0f + erfv);
}

// ---------------------------------------------------------------------------
// prepack: weights -> A-frag bf16 order; params -> packed fp32 array
// ---------------------------------------------------------------------------
__global__ void prepack_kernel(Params p, ushort* wf) {
  int f = blockIdx.x;
  int lane = threadIdx.x;

  if (f == NFRAG) {
    float* pw = (float*)(wf + (size_t)NFRAG * 512);
    for (int t = lane; t < NPARAM; t += 64) {
      float v = 0.f;
      if      (t < 64)   v = p.b_in[t];
      else if (t < 128)  v = p.g_in[t - 64];
      else if (t < 192)  v = p.be_in[t - 128];
      else if (t < 384)  v = p.z_in_b[t - 192];
      else if (t < 448)  v = p.z_out_b[t - 384];
      else if (t < 576)  v = p.z_ffn_b1[t - 448];
      else if (t < 640)  v = p.z_ffn_b2[t - 576];
      else if (t < 704)  v = p.zn1_g[t - 640];
      else if (t < 768)  v = p.zn1_b[t - 704];
      else if (t < 832)  v = p.zn2_g[t - 768];
      else if (t < 896)  v = p.zn2_b[t - 832];
      else if (t < 960)  v = p.y_in_b[128 + t - 896];
      else if (t < 1024) v = p.y_out_b[t - 960];
      else if (t < 1152) v = p.y_ffn_b1[t - 1024];
      else if (t < 1216) v = p.y_ffn_b2[t - 1152];
      else if (t < 1280) v = p.yn1_g[t - 1216];
      else if (t < 1344) v = p.yn1_b[t - 1280];
      else if (t < 1408) v = p.yn2_g[t - 1344];
      else if (t < 1472) v = p.yn2_b[t - 1408];
      else if (t < 1536) v = p.W_out[t - 1472];
      else if (t == 1536) v = p.b_out[0];
      pw[t] = v;
    }
    return;
  }

  int q = lane >> 4, r = lane & 15;
  const float* src; int K, mt, kt, l;
  if (f < 28)        { src = p.W_in;                K = 200; mt = f / 7;  kt = f % 7; }
  else if (f < 36)   { l = f - 28;  src = p.z_in_w;            K = 64;  mt = l / 2; kt = l % 2; }
  else if (f < 44)   { l = f - 36;  src = p.z_in_w + 64 * 64;  K = 64;  mt = l / 2; kt = l % 2; }
  else if (f < 52)   { l = f - 44;  src = p.z_in_w + 128 * 64; K = 64;  mt = l / 2; kt = l % 2; }
  else if (f < 60)   { l = f - 52;  src = p.z_out_w;           K = 64;  mt = l / 2; kt = l % 2; }
  else if (f < 76)   { l = f - 60;  src = p.z_ffn_w1;          K = 64;  mt = l / 2; kt = l % 2; }
  else if (f < 92)   { l = f - 76;  src = p.z_ffn_w2;          K = 128; mt = l / 4; kt = l % 4; }
  else if (f < 100)  { l = f - 92;  src = p.y_in_w + 128 * 64; K = 64;  mt = l / 2; kt = l % 2; }
  else if (f < 108)  { l = f - 100; src = p.y_out_w;           K = 64;  mt = l / 2; kt = l % 2; }
  else if (f < 124)  { l = f - 108; src = p.y_ffn_w1;          K = 64;  mt = l / 2; kt = l % 2; }
  else               { l = f - 124; src = p.y_ffn_w2;          K = 128; mt = l / 4; kt = l % 4; }

  int row = mt * 16 + r;
  int col = kt * 32 + q * 8;
  bfrag8 o;
#pragma unroll
  for (int j = 0; j < 8; ++j) {
    int cc = col + j;
    float v = (cc < K) ? src[(size_t)row * K + cc] : 0.0f;
    o[j] = (short)f2bf(v);
  }
  *(bfrag8*)(wf + (size_t)f * 512 + lane * 8) = o;
}

// ---------------------------------------------------------------------------
// main kernel: 1024 thr (16 waves) x 256 blocks; 4 waves/SIMD; weights in LDS.
// __launch_bounds__(1024, 1): 1 block/CU x 16 waves = 4 waves/EU -> 128-VGPR
// cap (the only allocator-control mechanism that has behaved consistently).
// ---------------------------------------------------------------------------
__global__ __launch_bounds__(1024, 1)
void trm_mfma_kernel(Params p, const ushort* wf) {
  __shared__ __align__(16) short arena[ARENA_SH];
  const int tid = threadIdx.x;
  const int wave = tid >> 6, lane = tid & 63;
  const int q = lane >> 4, s = lane & 15;

  // ---- stage steady weights + params into LDS (once per block) ----
  {
    const uint4* srcw = (const uint4*)(wf + (size_t)28 * 512);
    uint4* dstw = (uint4*)(arena + L_W);
    for (int i = tid; i < NSTEADY * 64; i += 1024) dstw[i] = srcw[i];
    const uint4* srcp = (const uint4*)(wf + (size_t)NFRAG * 512);
    uint4* dstp = (uint4*)(arena + L_P);
    for (int i = tid; i < NPARAM / 4; i += 1024) dstp[i] = srcp[i];
  }
  __syncthreads();  // the only barrier

  const short* LW = arena + L_W;
  const float* P  = (const float*)(arena + L_P);
  short* TH = arena + L_ACT + wave * WAVE_SH;

  const int chunks = (p.nrows + 255) / 256;
  for (int ic = blockIdx.x; ic < chunks; ic += gridDim.x) {
    const int row0 = ic * 256 + wave * 16;
    int row = row0 + s;
    if (row >= p.nrows) row = p.nrows - 1;

    // ---- x_proj = gelu(ln(x @ W_in^T + b_in)); stays in registers ----
    bfrag8 xpB[2];
    {
      const float* xr = p.x + (size_t)row * INDIM;
      bfrag8 xb[7];
#pragma unroll
      for (int kt = 0; kt < 7; ++kt) {
        int k0i = kt * 32 + q * 8;
        bfrag8 t;
        if (kt < 6 || q == 0) {
          f32x4 lo = *(const f32x4*)(xr + k0i);
          f32x4 hi = *(const f32x4*)(xr + k0i + 4);
          t[0] = (short)f2bf(lo.x); t[1] = (short)f2bf(lo.y);
          t[2] = (short)f2bf(lo.z); t[3] = (short)f2bf(lo.w);
          t[4] = (short)f2bf(hi.x); t[5] = (short)f2bf(hi.y);
          t[6] = (short)f2bf(hi.z); t[7] = (short)f2bf(hi.w);
        } else {
#pragma unroll
          for (int j = 0; j < 8; ++j) t[j] = 0;
        }
        xb[kt] = t;
      }
      f32x4 c[4];
#pragma unroll
      for (int mt = 0; mt < 4; ++mt)
        c[mt] = *(const f32x4*)(P + PB_BIN + mt * 16 + q * 4);
#pragma unroll
      for (int mt = 0; mt < 4; ++mt)
#pragma unroll
        for (int kt = 0; kt < 7; ++kt) {
          bfrag8 af =
              *(const bfrag8*)(wf + (size_t)(FB_WIN + mt * 7 + kt) * 512 + lane * 8);
          c[mt] = __builtin_amdgcn_mfma_f32_16x16x32_bf16(af, xb[kt], c[mt], 0, 0, 0);
        }
      lnorm_c(c, P + PB_GIN, P + PB_BEIN, q);
#pragma unroll
      for (int mt = 0; mt < 4; ++mt) {
        c[mt].x = gelu1(c[mt].x); c[mt].y = gelu1(c[mt].y);
        c[mt].z = gelu1(c[mt].z); c[mt].w = gelu1(c[mt].w);
      }
      c2b(c, xpB[0], xpB[1], lane);
    }

    // ---- k0/v0 packed bf16 in registers; zero state ----
    uint k0p[8], v0p[8], zCp[8], yCp[8];
    bfrag8 zB[2], yB[2];
    {
      f32x4 ck[4], cv[4];
      layerBK<4, 2>(xpB, LW, LB_ZK, P + PB_ZINB + 64, ck, lane, q);
      layerBK<4, 2>(xpB, LW, LB_ZV, P + PB_ZINB + 128, cv, lane, q);
#pragma unroll
      for (int mt = 0; mt < 4; ++mt) {
        k0p[2 * mt]     = pk2(ck[mt].x, ck[mt].y);
        k0p[2 * mt + 1] = pk2(ck[mt].z, ck[mt].w);
        v0p[2 * mt]     = pk2(cv[mt].x, cv[mt].y);
        v0p[2 * mt + 1] = pk2(cv[mt].z, cv[mt].w);
        zCp[2 * mt] = 0u; zCp[2 * mt + 1] = 0u;
        yCp[2 * mt] = 0u; yCp[2 * mt + 1] = 0u;
      }
#pragma unroll
      for (int kt = 0; kt < 2; ++kt) {
        bfrag8 t;
#pragma unroll
        for (int j = 0; j < 8; ++j) t[j] = 0;
        zB[kt] = t; yB[kt] = t;
      }
    }

    // ---- 16 recursive steps ----
    for (int st = 0; st < STEPS; ++st) {
      // -- attention k-phase: scores + softmax, k regs freed after --
      float w0[4], w1[4], w2[4], wi[4];
      {
        f32x4 q2[4], kz[4], ky[4];
        layerBK<4, 2>(zB, LW, LB_ZQ, P + PB_ZINB, q2, lane, q);
        layerB2<4>(zB, yB, LW, LB_ZK, P + PB_ZINB + 64, kz, ky, lane, q);
#pragma unroll
        for (int mt = 0; mt < 4; ++mt) {
          float a0 = q2[mt].x * upk_lo(k0p[2 * mt]) +
                     q2[mt].y * upk_hi(k0p[2 * mt]) +
                     q2[mt].z * upk_lo(k0p[2 * mt + 1]) +
                     q2[mt].w * upk_hi(k0p[2 * mt + 1]);
          float a1 = dot4(q2[mt], ky[mt]);
          float a2 = dot4(q2[mt], kz[mt]);
          a0 += __shfl_xor(a0, 16); a0 += __shfl_xor(a0, 32);
          a1 += __shfl_xor(a1, 16); a1 += __shfl_xor(a1, 32);
          a2 += __shfl_xor(a2, 16); a2 += __shfl_xor(a2, 32);
          a0 *= 0.25f; a1 *= 0.25f; a2 *= 0.25f;
          float mx = fmaxf(a0, fmaxf(a1, a2));
          float e0 = __expf(a0 - mx), e1 = __expf(a1 - mx), e2 = __expf(a2 - mx);
          w0[mt] = e0; w1[mt] = e1; w2[mt] = e2;
          wi[mt] = __builtin_amdgcn_rcpf(e0 + e1 + e2);
        }
      }
      // -- attention v-phase --
      {
        f32x4 vz[4], vy[4];
        layerB2<4>(zB, yB, LW, LB_ZV, P + PB_ZINB + 128, vz, vy, lane, q);
#pragma unroll
        for (int mt = 0; mt < 4; ++mt) {
          f32x4 o;
          o.x = (upk_lo(v0p[2 * mt])     * w0[mt] + vy[mt].x * w1[mt] +
                 vz[mt].x * w2[mt]) * wi[mt];
          o.y = (upk_hi(v0p[2 * mt])     * w0[mt] + vy[mt].y * w1[mt] +
                 vz[mt].y * w2[mt]) * wi[mt];
          o.z = (upk_lo(v0p[2 * mt + 1]) * w0[mt] + vy[mt].z * w1[mt] +
                 vz[mt].z * w2[mt]) * wi[mt];
          o.w = (upk_hi(v0p[2 * mt + 1]) * w0[mt] + vy[mt].w * w1[mt] +
                 vz[mt].w * w2[mt]) * wi[mt];
          stc(TH, S64, mt, q, s, o);
        }
      }

      // -- z branch --
      uint zrp[8];
      {
        f32x4 zr[4];
        layerN<4>(TH, LW, LB_ZOUT, P + PB_ZOUTB, zr, lane, q, s);
#pragma unroll
        for (int mt = 0; mt < 4; ++mt) {
          zr[mt].x += upk_lo(zCp[2 * mt]);     zr[mt].y += upk_hi(zCp[2 * mt]);
          zr[mt].z += upk_lo(zCp[2 * mt + 1]); zr[mt].w += upk_hi(zCp[2 * mt + 1]);
        }
        lnorm_c(zr, P + PB_ZN1G, P + PB_ZN1B, q);
#pragma unroll
        for (int mt = 0; mt < 4; ++mt) {
          stc(TH, S64, mt, q, s, zr[mt]);
          zrp[2 * mt]     = pk2(zr[mt].x, zr[mt].y);
          zrp[2 * mt + 1] = pk2(zr[mt].z, zr[mt].w);
        }
      }

      // z-FFN: h = gelu(W1*zr+b1) entirely in regs -> 4 B-frags via c2b
      bfrag8 hB[4];
      {
        f32x4 h8[8];
        layerN<8>(TH, LW, LB_ZF1, P + PB_ZF1B, h8, lane, q, s);
#pragma unroll
        for (int g = 0; g < 2; ++g) {
          uint ph[8];
#pragma unroll
          for (int mt = 0; mt < 4; ++mt) {
            f32x4 h = h8[4 * g + mt];
            h.x = gelu1(h.x); h.y = gelu1(h.y);
            h.z = gelu1(h.z); h.w = gelu1(h.w);
            ph[2 * mt]     = pk2(h.x, h.y);
            ph[2 * mt + 1] = pk2(h.z, h.w);
          }
          c2b_p(ph, hB[2 * g], hB[2 * g + 1], lane);
        }
      }
      f32x4 z2[4];
      layerBK<4, 4>(hB, LW, LB_ZF2, P + PB_ZF2B, z2, lane, q);
#pragma unroll
      for (int mt = 0; mt < 4; ++mt) {
        z2[mt].x += upk_lo(zrp[2 * mt]);     z2[mt].y += upk_hi(zrp[2 * mt]);
        z2[mt].z += upk_lo(zrp[2 * mt + 1]); z2[mt].w += upk_hi(zrp[2 * mt + 1]);
      }
      lnorm_c(z2, P + PB_ZN2G, P + PB_ZN2B, q);
      {
        uint zp[8];
#pragma unroll
        for (int mt = 0; mt < 4; ++mt) {
          zp[2 * mt]     = pk2(z2[mt].x, z2[mt].y);
          zp[2 * mt + 1] = pk2(z2[mt].z, z2[mt].w);
          zCp[2 * mt] = zp[2 * mt]; zCp[2 * mt + 1] = zp[2 * mt + 1];
        }
        c2b_p(zp, zB[0], zB[1], lane);
      }

      // -- y branch --
      f32x4 t4[4];
      layerBK<4, 2>(zB, LW, LB_YV, P + PB_YVB, t4, lane, q);
#pragma unroll
      for (int mt = 0; mt < 4; ++mt) stc(TH, S64, mt, q, s, t4[mt]);

      uint yrp[8];
      {
        f32x4 yr[4];
        layerN<4>(TH, LW, LB_YOUT, P + PB_YOUTB, yr, lane, q, s);
#pragma unroll
        for (int mt = 0; mt < 4; ++mt) {
          yr[mt].x += upk_lo(yCp[2 * mt]);     yr[mt].y += upk_hi(yCp[2 * mt]);
          yr[mt].z += upk_lo(yCp[2 * mt + 1]); yr[mt].w += upk_hi(yCp[2 * mt + 1]);
        }
        lnorm_c(yr, P + PB_YN1G, P + PB_YN1B, q);
#pragma unroll
        for (int mt = 0; mt < 4; ++mt) {
          stc(TH, S64, mt, q, s, yr[mt]);
          yrp[2 * mt]     = pk2(yr[mt].x, yr[mt].y);
          yrp[2 * mt + 1] = pk2(yr[mt].z, yr[mt].w);
        }
      }

      // y-FFN: same register-resident h path
      {
        f32x4 h8[8];
        layerN<8>(TH, LW, LB_YF1, P + PB_YF1B, h8, lane, q, s);
#pragma unroll
        for (int g = 0; g < 2; ++g) {
          uint ph[8];
#pragma unroll
          for (int mt = 0; mt < 4; ++mt) {
            f32x4 h = h8[4 * g + mt];
            h.x = gelu1(h.x); h.y = gelu1(h.y);
            h.z = gelu1(h.z); h.w = gelu1(h.w);
            ph[2 * mt]     = pk2(h.x, h.y);
            ph[2 * mt + 1] = pk2(h.z, h.w);
          }
          c2b_p(ph, hB[2 * g], hB[2 * g + 1], lane);
        }
      }
      f32x4 y2[4];
      layerBK<4, 4>(hB, LW, LB_YF2, P + PB_YF2B, y2, lane, q);
#pragma unroll
      for (int mt = 0; mt < 4; ++mt) {
        y2[mt].x += upk_lo(yrp[2 * mt]);     y2[mt].y += upk_hi(yrp[2 * mt]);
        y2[mt].z += upk_lo(yrp[2 * mt + 1]); y2[mt].w += upk_hi(yrp[2 * mt + 1]);
      }
      lnorm_c(y2, P + PB_YN2G, P + PB_YN2B, q);
      {
        uint yp[8];
#pragma unroll
        for (int mt = 0; mt < 4; ++mt) {
          yp[2 * mt]     = pk2(y2[mt].x, y2[mt].y);
          yp[2 * mt + 1] = pk2(y2[mt].z, y2[mt].w);
          yCp[2 * mt] = yp[2 * mt]; yCp[2 * mt + 1] = yp[2 * mt + 1];
        }
        c2b_p(yp, yB[0], yB[1], lane);
      }
    }

    // ---- out = (y @ W_out^T + b_out)[:, 0] from packed carry ----
    float acc = 0.f;
#pragma unroll
    for (int mt = 0; mt < 4; ++mt) {
      f32x4 w4 = *(const f32x4*)(P + PB_WOUT + mt * 16 + q * 4);
      acc += upk_lo(yCp[2 * mt]) * w4.x + upk_hi(yCp[2 * mt]) * w4.y +
             upk_lo(yCp[2 * mt + 1]) * w4.z + upk_hi(yCp[2 * mt + 1]) * w4.w;
    }
    acc += __shfl_xor(acc, 16); acc += __shfl_xor(acc, 32);
    if (q == 0 && (row0 + s) < p.nrows) p.out[row0 + s] = acc + P[PB_BOUT];
  }
}

extern "C" void kernel_launch(void* const* d_in, const int* in_sizes, int n_in,
                              void* d_out, int out_size, void* d_ws,
                              size_t ws_size, hipStream_t stream) {
  Params p;
  const float* const* in = (const float* const*)d_in;
  p.x        = in[0];  p.W_in     = in[1];  p.b_in     = in[2];
  p.g_in     = in[3];  p.be_in    = in[4];
  p.z_in_w   = in[5];  p.z_in_b   = in[6];
  p.z_out_w  = in[7];  p.z_out_b  = in[8];
  p.z_ffn_w1 = in[9];  p.z_ffn_b1 = in[10];
  p.z_ffn_w2 = in[11]; p.z_ffn_b2 = in[12];
  p.zn1_g    = in[13]; p.zn1_b    = in[14];
  p.zn2_g    = in[15]; p.zn2_b    = in[16];
  p.y_in_w   = in[17]; p.y_in_b   = in[18];
  p.y_out_w  = in[19]; p.y_out_b  = in[20];
  p.y_ffn_w1 = in[21]; p.y_ffn_b1 = in[22];
  p.y_ffn_w2 = in[23]; p.y_ffn_b2 = in[24];
  p.yn1_g    = in[25]; p.yn1_b    = in[26];
  p.yn2_g    = in[27]; p.yn2_b    = in[28];
  p.W_out    = in[29]; p.b_out    = in[30];
  p.out      = (float*)d_out;
  p.nrows    = in_sizes[0] / INDIM;

  if (ws_size < (size_t)NFRAG * 1024 + NPARAM * 4) return;
  ushort* wf = (ushort*)d_ws;

  hipLaunchKernelGGL(prepack_kernel, dim3(NFRAG + 1), dim3(64), 0, stream, p, wf);
  hipLaunchKernelGGL(trm_mfma_kernel, dim3(256), dim3(1024), 0, stream, p, wf);
}